// Round 1
// baseline (11092.763 us; speedup 1.0000x reference)
//
#include <hip/hip_runtime.h>
#include <math.h>

#define BB 4
#define TT 12
#define NN 2000
#define CC 8
#define HH 64
#define EE 32000
#define NHEADS 8
#define HD 8
#define HORZ 12
#define BT (BB*TT)        // 48
#define RR (BT*NN)        // 96000 rows of H=64

__device__ __forceinline__ float sigmoidf_(float x){ return 1.0f/(1.0f+__expf(-x)); }
__device__ __forceinline__ float siluf_(float x){ return x/(1.0f+__expf(-x)); }

// ---------------- up-projection: h = relu(x @ up_w + up_b) ----------------
// wave per row, lane j = output col. x row (8 floats) read wave-uniformly.
__global__ void k_up(const float* __restrict__ x, const float* __restrict__ w,
                     const float* __restrict__ b, float* __restrict__ h) {
    int gid = blockIdx.x*blockDim.x + threadIdx.x;
    int r = gid >> 6;
    int j = gid & 63;
    if (r >= RR) return;
    int ru = __builtin_amdgcn_readfirstlane(r);
    float acc = b[j];
    #pragma unroll
    for (int c = 0; c < CC; ++c)
        acc += x[ru*CC + c] * w[c*HH + j];
    h[(size_t)ru*HH + j] = fmaxf(acc, 0.0f);
}

// ---------------- spatial message + gate + scatter-add ----------------
// block = 1 wave = 64 edges for one (b,t). cat rows (xi||xj) staged in LDS
// (pad 129 -> bank (t+c)%32, 2-way = free). Weights via wave-uniform loads.
__global__ __launch_bounds__(64) void k_msg(
    const float* __restrict__ h, const int* __restrict__ eidx,
    const float* __restrict__ w1, const float* __restrict__ b1,
    const float* __restrict__ w2, const float* __restrict__ b2,
    const float* __restrict__ gw, const float* __restrict__ gb,
    float* __restrict__ agg)
{
    const int EB = EE/64; // 500
    int eb = blockIdx.x % EB;
    int bt = blockIdx.x / EB;
    int t  = threadIdx.x;

    __shared__ float cat[64][129];

    int e0 = eb*64;
    int my_src = eidx[e0 + t];        // edge_index[0] = src
    int my_tgt = eidx[EE + e0 + t];   // edge_index[1] = tgt
    const float* hb = h + (size_t)bt*NN*HH;

    #pragma unroll 8
    for (int e = 0; e < 64; ++e) {
        int s = __shfl(my_src, e);
        int g = __shfl(my_tgt, e);
        cat[e][t]      = hb[(size_t)g*HH + t];   // xi = h[tgt]
        cat[e][64 + t] = hb[(size_t)s*HH + t];   // xj = h[src]
    }
    __syncthreads();

    float m1[32];
    #pragma unroll
    for (int k2 = 0; k2 < 32; ++k2) m1[k2] = b1[k2];
    #pragma unroll 2
    for (int c = 0; c < 128; ++c) {
        float v = cat[t][c];
        #pragma unroll
        for (int k2 = 0; k2 < 32; ++k2) m1[k2] += v * w1[c*32 + k2];
    }
    #pragma unroll
    for (int k2 = 0; k2 < 32; ++k2) m1[k2] = siluf_(m1[k2]);

    float m2[64];
    #pragma unroll
    for (int j = 0; j < 64; ++j) m2[j] = b2[j];
    #pragma unroll 2
    for (int k2 = 0; k2 < 32; ++k2) {
        float v = m1[k2];
        #pragma unroll
        for (int j = 0; j < 64; ++j) m2[j] += v * w2[k2*64 + j];
    }
    float g = gb[0];
    #pragma unroll
    for (int j = 0; j < 64; ++j) { m2[j] = siluf_(m2[j]); g += m2[j]*gw[j]; }
    g = sigmoidf_(g);

    float* ab = agg + ((size_t)bt*NN + my_tgt)*HH;
    #pragma unroll
    for (int j = 0; j < 64; ++j) atomicAdd(&ab[j], g*m2[j]);
}

// ---------------- spatial update: out = silu([agg,h]@w1+b1)@w2+b2 + h ----
__global__ void k_upd(const float* __restrict__ h, const float* __restrict__ agg,
                      const float* __restrict__ w1, const float* __restrict__ b1,
                      const float* __restrict__ w2, const float* __restrict__ b2,
                      float* __restrict__ out, int do_relu)
{
    int gid = blockIdx.x*blockDim.x + threadIdx.x;
    int r = gid >> 6; int j = gid & 63;
    if (r >= RR) return;
    int ru = __builtin_amdgcn_readfirstlane(r);
    const float* ar = agg + (size_t)ru*HH;
    const float* hr = h   + (size_t)ru*HH;
    float acc = b1[j];
    #pragma unroll 8
    for (int c = 0; c < 64; ++c) acc += ar[c]*w1[c*64 + j];
    #pragma unroll 8
    for (int c = 0; c < 64; ++c) acc += hr[c]*w1[(64+c)*64 + j];
    float u1 = siluf_(acc);
    float acc2 = b2[j];
    #pragma unroll 8
    for (int k2 = 0; k2 < 64; ++k2) acc2 += __shfl(u1, k2) * w2[k2*64 + j];
    float o = acc2 + hr[j];
    if (do_relu) o = fmaxf(o, 0.f);
    out[(size_t)ru*HH + j] = o;
}

// ---------------- fused QKV projection ----------------
__global__ void k_qkv(const float* __restrict__ h,
                      const float* __restrict__ wq, const float* __restrict__ wk,
                      const float* __restrict__ wv,
                      const float* __restrict__ bq, const float* __restrict__ bk,
                      const float* __restrict__ bv,
                      float* __restrict__ q, float* __restrict__ k, float* __restrict__ v)
{
    int gid = blockIdx.x*blockDim.x + threadIdx.x;
    int r = gid >> 6; int j = gid & 63;
    if (r >= RR) return;
    int ru = __builtin_amdgcn_readfirstlane(r);
    const float* hr = h + (size_t)ru*HH;
    float aq = bq[j], ak = bk[j], av = bv[j];
    #pragma unroll 8
    for (int c = 0; c < 64; ++c) {
        float s = hr[c];
        aq += s*wq[c*64 + j];
        ak += s*wk[c*64 + j];
        av += s*wv[c*64 + j];
    }
    q[(size_t)ru*HH + j] = aq;
    k[(size_t)ru*HH + j] = ak;
    v[(size_t)ru*HH + j] = av;
}

// ---------------- temporal attention (T=12, per (b,n,head,s) thread) ------
__global__ void k_attn(const float* __restrict__ q, const float* __restrict__ k,
                       const float* __restrict__ v, float* __restrict__ o)
{
    int gid = blockIdx.x*blockDim.x + threadIdx.x;
    if (gid >= BB*NN*NHEADS*TT) return;
    int s    = gid % TT;
    int head = (gid/TT) % NHEADS;
    int n    = (gid/(TT*NHEADS)) % NN;
    int b    = gid/(TT*NHEADS*NN);

    float qv[HD];
    size_t qoff = ((size_t)(b*TT + s)*NN + n)*HH + head*HD;
    #pragma unroll
    for (int d = 0; d < HD; ++d) qv[d] = q[qoff + d];

    float sc[TT]; float mx = -1e30f;
    #pragma unroll
    for (int t = 0; t < TT; ++t) {
        size_t koff = ((size_t)(b*TT + t)*NN + n)*HH + head*HD;
        float a = 0.f;
        #pragma unroll
        for (int d = 0; d < HD; ++d) a += qv[d]*k[koff + d];
        a *= 0.35355339059327373f; // 1/sqrt(8)
        sc[t] = a; mx = fmaxf(mx, a);
    }
    float sum = 0.f;
    #pragma unroll
    for (int t = 0; t < TT; ++t) { sc[t] = __expf(sc[t]-mx); sum += sc[t]; }
    float inv = 1.0f/sum;
    float ov[HD];
    #pragma unroll
    for (int d = 0; d < HD; ++d) ov[d] = 0.f;
    #pragma unroll
    for (int t = 0; t < TT; ++t) {
        size_t voff = ((size_t)(b*TT + t)*NN + n)*HH + head*HD;
        float a = sc[t]*inv;
        #pragma unroll
        for (int d = 0; d < HD; ++d) ov[d] += a*v[voff + d];
    }
    #pragma unroll
    for (int d = 0; d < HD; ++d) o[qoff + d] = ov[d];
}

// ---------------- generic 64x64 row-GEMM: out = in @ w + b ----------------
__global__ void k_rowgemm64(const float* __restrict__ in, const float* __restrict__ w,
                            const float* __restrict__ b, float* __restrict__ out)
{
    int gid = blockIdx.x*blockDim.x + threadIdx.x;
    int r = gid >> 6; int j = gid & 63;
    if (r >= RR) return;
    int ru = __builtin_amdgcn_readfirstlane(r);
    const float* ir = in + (size_t)ru*HH;
    float acc = b[j];
    #pragma unroll 8
    for (int c = 0; c < 64; ++c) acc += ir[c]*w[c*64 + j];
    out[(size_t)ru*HH + j] = acc;
}

// ---------------- fused conv(T->HOR) + MLP head ----------------
// thread per (b,hor,n): z[72] = [h(64)||x(8)] conv over t; then 72->64 relu -> 8.
__global__ void k_convmlp(const float* __restrict__ h, const float* __restrict__ x,
                          const float* __restrict__ cw, const float* __restrict__ cb,
                          const float* __restrict__ w1, const float* __restrict__ b1,
                          const float* __restrict__ w2, const float* __restrict__ b2,
                          float* __restrict__ out)
{
    int gid = blockIdx.x*blockDim.x + threadIdx.x;
    if (gid >= BB*HORZ*NN) return;
    int n   = gid % NN;
    int hor = (gid/NN) % HORZ;
    int b   = gid/(NN*HORZ);

    float cwv[TT];
    #pragma unroll
    for (int t = 0; t < TT; ++t) cwv[t] = cw[hor*TT + t];
    float cbv = cb[hor];

    float z[72];
    #pragma unroll
    for (int c = 0; c < 72; ++c) z[c] = cbv;
    for (int t = 0; t < TT; ++t) {
        const float* hrow = h + ((size_t)(b*TT + t)*NN + n)*HH;
        const float* xrow = x + ((size_t)(b*TT + t)*NN + n)*CC;
        float wv = cwv[t];
        #pragma unroll
        for (int c = 0; c < 64; ++c) z[c]    += hrow[c]*wv;
        #pragma unroll
        for (int c = 0; c < 8; ++c)  z[64+c] += xrow[c]*wv;
    }

    float hid[64];
    #pragma unroll
    for (int k2 = 0; k2 < 64; ++k2) hid[k2] = b1[k2];
    #pragma unroll 2
    for (int c = 0; c < 72; ++c) {
        float v = z[c];
        #pragma unroll
        for (int k2 = 0; k2 < 64; ++k2) hid[k2] += v*w1[c*64 + k2];
    }
    #pragma unroll
    for (int k2 = 0; k2 < 64; ++k2) hid[k2] = fmaxf(hid[k2], 0.f);

    float o[8];
    #pragma unroll
    for (int c2 = 0; c2 < 8; ++c2) o[c2] = b2[c2];
    #pragma unroll 8
    for (int k2 = 0; k2 < 64; ++k2) {
        float v = hid[k2];
        #pragma unroll
        for (int c2 = 0; c2 < 8; ++c2) o[c2] += v*w2[k2*8 + c2];
    }
    size_t ooff = ((size_t)(b*HORZ + hor)*NN + n)*CC;
    #pragma unroll
    for (int c2 = 0; c2 < 8; ++c2) out[ooff + c2] = o[c2];
}

extern "C" void kernel_launch(void* const* d_in, const int* in_sizes, int n_in,
                              void* d_out, int out_size, void* d_ws, size_t ws_size,
                              hipStream_t stream) {
    const float* x    = (const float*)d_in[0];
    const int*   eidx = (const int*)d_in[1];
    const float* up_w = (const float*)d_in[2];
    const float* up_b = (const float*)d_in[3];
    // sp1: 4..13, sp2: 14..23
    const float* sp_w[2][10];
    for (int p = 0; p < 2; ++p)
        for (int i = 0; i < 10; ++i)
            sp_w[p][i] = (const float*)d_in[4 + p*10 + i];
    const float* wq = (const float*)d_in[24];
    const float* wk = (const float*)d_in[25];
    const float* wv = (const float*)d_in[26];
    const float* wo = (const float*)d_in[27];
    const float* bq = (const float*)d_in[28];
    const float* bk = (const float*)d_in[29];
    const float* bv = (const float*)d_in[30];
    const float* bo = (const float*)d_in[31];
    const float* conv_w = (const float*)d_in[32];
    const float* conv_b = (const float*)d_in[33];
    const float* mlp_w1 = (const float*)d_in[34];
    const float* mlp_b1 = (const float*)d_in[35];
    const float* mlp_w2 = (const float*)d_in[36];
    const float* mlp_b2 = (const float*)d_in[37];
    float* out = (float*)d_out;

    const size_t BUF = (size_t)RR*HH;      // 6,144,000 floats
    float* A   = (float*)d_ws;             // h
    float* Bb  = A  + BUF;                 // h2
    float* AGG = Bb + BUF;                 // agg / K
    float* Vb  = AGG + BUF;                // V
    float* Ob  = Vb + BUF;                 // attn out

    const int ROWGRID = (RR*64)/256;       // 24000 blocks of 256

    // 1. up-projection
    k_up<<<ROWGRID, 256, 0, stream>>>(x, up_w, up_b, A);

    // 2. spatial 1
    hipMemsetAsync(AGG, 0, BUF*sizeof(float), stream);
    k_msg<<<BT*(EE/64), 64, 0, stream>>>(A, eidx,
        sp_w[0][0], sp_w[0][1], sp_w[0][2], sp_w[0][3], sp_w[0][4], sp_w[0][5], AGG);
    k_upd<<<ROWGRID, 256, 0, stream>>>(A, AGG,
        sp_w[0][6], sp_w[0][7], sp_w[0][8], sp_w[0][9], Bb, 1);

    // 3. temporal: QKV (Q->A, K->AGG, V->Vb), attn -> Ob, proj -> A
    k_qkv<<<ROWGRID, 256, 0, stream>>>(Bb, wq, wk, wv, bq, bk, bv, A, AGG, Vb);
    k_attn<<<(BB*NN*NHEADS*TT + 255)/256, 256, 0, stream>>>(A, AGG, Vb, Ob);
    k_rowgemm64<<<ROWGRID, 256, 0, stream>>>(Ob, wo, bo, A);

    // 4. spatial 2
    hipMemsetAsync(AGG, 0, BUF*sizeof(float), stream);
    k_msg<<<BT*(EE/64), 64, 0, stream>>>(A, eidx,
        sp_w[1][0], sp_w[1][1], sp_w[1][2], sp_w[1][3], sp_w[1][4], sp_w[1][5], AGG);
    k_upd<<<ROWGRID, 256, 0, stream>>>(A, AGG,
        sp_w[1][6], sp_w[1][7], sp_w[1][8], sp_w[1][9], Bb, 1);

    // 5. conv + MLP head -> out
    k_convmlp<<<(BB*HORZ*NN + 255)/256, 256, 0, stream>>>(Bb, x,
        conv_w, conv_b, mlp_w1, mlp_b1, mlp_w2, mlp_b2, out);
}

// Round 2
// 1222.062 us; speedup vs baseline: 9.0771x; 9.0771x over previous
//
#include <hip/hip_runtime.h>
#include <math.h>

#define BB 4
#define TT 12
#define NN 2000
#define CC 8
#define HH 64
#define EE 32000
#define NHEADS 8
#define HD 8
#define HORZ 12
#define BT (BB*TT)        // 48
#define RR (BT*NN)        // 96000 rows of H=64

__device__ __forceinline__ float sigmoidf_(float x){ return 1.0f/(1.0f+__expf(-x)); }
__device__ __forceinline__ float siluf_(float x){ return x/(1.0f+__expf(-x)); }

// ================= CSR build (edges sorted by tgt) =================
__global__ void k_hist(const int* __restrict__ eidx, int* __restrict__ cnt) {
    int e = blockIdx.x*blockDim.x + threadIdx.x;
    if (e < EE) atomicAdd(&cnt[eidx[EE + e]], 1);
}

// exclusive scan over 2000 counts (pad 2048), one block of 256
__global__ __launch_bounds__(256) void k_scan(const int* __restrict__ cnt,
                                              int* __restrict__ ofs_work) {
    __shared__ int part[256];
    int tid = threadIdx.x;
    int local[8]; int s = 0;
    #pragma unroll
    for (int k = 0; k < 8; ++k) {
        int idx = tid*8 + k;
        int v = (idx < NN) ? cnt[idx] : 0;
        local[k] = s; s += v;
    }
    part[tid] = s; __syncthreads();
    for (int off = 1; off < 256; off <<= 1) {
        int v = part[tid];
        int u = (tid >= off) ? part[tid-off] : 0;
        __syncthreads();
        part[tid] = v + u;
        __syncthreads();
    }
    int excl = part[tid] - s;
    #pragma unroll
    for (int k = 0; k < 8; ++k) {
        int idx = tid*8 + k;
        if (idx < NN) ofs_work[idx] = excl + local[k];
    }
}

__global__ void k_scatter(const int* __restrict__ eidx, int* __restrict__ ofs_work,
                          int* __restrict__ ssrc, int* __restrict__ stgt) {
    int e = blockIdx.x*blockDim.x + threadIdx.x;
    if (e >= EE) return;
    int t = eidx[EE + e];
    int pos = atomicAdd(&ofs_work[t], 1);
    ssrc[pos] = eidx[e];
    stgt[pos] = t;
}

// ========== per-node precompute of first msg-MLP layer ==========
// preW[row][j]: j<32 -> (h_row @ W1_top)[j]  (xi part),
//              j>=32 -> (h_row @ W1_bot)[j-32] (xj part)
__global__ void k_pre(const float* __restrict__ h, const float* __restrict__ w1,
                      float* __restrict__ preW) {
    int gid = blockIdx.x*blockDim.x + threadIdx.x;
    int r = gid >> 6; int j = gid & 63;
    if (r >= RR) return;
    int ru = __builtin_amdgcn_readfirstlane(r);
    const float* hr = h + (size_t)ru*HH;
    int base = (j < 32) ? j : (2048 + j - 32);   // (64+c)*32+(j-32) = 2048 + c*32 + (j-32)
    float acc = 0.f;
    #pragma unroll 8
    for (int c = 0; c < 64; ++c) acc += hr[c]*w1[c*32 + base];
    preW[(size_t)ru*HH + j] = acc;
}

// ========== message MLP + gate + segmented scatter (sorted edges) ==========
__global__ __launch_bounds__(64) void k_msg(
    const float* __restrict__ preW, const int* __restrict__ ssrc,
    const int* __restrict__ stgt,
    const float* __restrict__ b1,
    const float* __restrict__ w2, const float* __restrict__ b2,
    const float* __restrict__ gw, const float* __restrict__ gb,
    float* __restrict__ agg)
{
    const int EB = EE/64; // 500
    int eb = blockIdx.x % EB;
    int bt = blockIdx.x / EB;
    int t  = threadIdx.x;

    __shared__ float cat[64][65];

    int e0 = eb*64;
    int my_src = ssrc[e0 + t];
    int my_tgt = stgt[e0 + t];
    const float* pw = preW + (size_t)bt*NN*HH;

    // gather: edge e needs xiW[tgt_e][0:32] (lanes 0-31) and xjW[src_e][0:32] (lanes 32-63)
    #pragma unroll 8
    for (int e = 0; e < 64; ++e) {
        int s = __shfl(my_src, e);
        int g = __shfl(my_tgt, e);
        int node = (t < 32) ? g : s;
        cat[e][t] = pw[(size_t)node*HH + t];
    }
    __syncthreads();

    // thread t computes edge (e0+t)
    float m1[32];
    #pragma unroll
    for (int k2 = 0; k2 < 32; ++k2)
        m1[k2] = siluf_(cat[t][k2] + cat[t][32 + k2] + b1[k2]);

    float m2[64];
    #pragma unroll
    for (int j = 0; j < 64; ++j) m2[j] = b2[j];
    #pragma unroll 2
    for (int k2 = 0; k2 < 32; ++k2) {
        float v = m1[k2];
        #pragma unroll
        for (int j = 0; j < 64; ++j) m2[j] += v * w2[k2*64 + j];
    }
    float g = gb[0];
    #pragma unroll
    for (int j = 0; j < 64; ++j) { m2[j] = siluf_(m2[j]); g += m2[j]*gw[j]; }
    g = sigmoidf_(g);

    __syncthreads();  // all reads of cat rows done (own-row only, but be safe)
    #pragma unroll
    for (int j = 0; j < 64; ++j) cat[t][j] = g * m2[j];
    __syncthreads();

    // segmented reduction: lane t = feature t, scan edges 0..63 (sorted by tgt)
    float* ab = agg + (size_t)bt*NN*HH;
    float acc = 0.f;
    int prev = __shfl(my_tgt, 0);
    for (int e = 0; e < 64; ++e) {
        int te = __shfl(my_tgt, e);        // wave-uniform
        if (te != prev) {                   // uniform branch
            atomicAdd(&ab[(size_t)prev*HH + t], acc);
            acc = 0.f; prev = te;
        }
        acc += cat[e][t];
    }
    atomicAdd(&ab[(size_t)prev*HH + t], acc);
}

// ---------------- up-projection: h = relu(x @ up_w + up_b) ----------------
__global__ void k_up(const float* __restrict__ x, const float* __restrict__ w,
                     const float* __restrict__ b, float* __restrict__ h) {
    int gid = blockIdx.x*blockDim.x + threadIdx.x;
    int r = gid >> 6;
    int j = gid & 63;
    if (r >= RR) return;
    int ru = __builtin_amdgcn_readfirstlane(r);
    float acc = b[j];
    #pragma unroll
    for (int c = 0; c < CC; ++c)
        acc += x[ru*CC + c] * w[c*HH + j];
    h[(size_t)ru*HH + j] = fmaxf(acc, 0.0f);
}

// ---------------- spatial update: out = silu([agg,h]@w1+b1)@w2+b2 + h ----
__global__ void k_upd(const float* __restrict__ h, const float* __restrict__ agg,
                      const float* __restrict__ w1, const float* __restrict__ b1,
                      const float* __restrict__ w2, const float* __restrict__ b2,
                      float* __restrict__ out, int do_relu)
{
    int gid = blockIdx.x*blockDim.x + threadIdx.x;
    int r = gid >> 6; int j = gid & 63;
    if (r >= RR) return;
    int ru = __builtin_amdgcn_readfirstlane(r);
    const float* ar = agg + (size_t)ru*HH;
    const float* hr = h   + (size_t)ru*HH;
    float acc = b1[j];
    #pragma unroll 8
    for (int c = 0; c < 64; ++c) acc += ar[c]*w1[c*64 + j];
    #pragma unroll 8
    for (int c = 0; c < 64; ++c) acc += hr[c]*w1[(64+c)*64 + j];
    float u1 = siluf_(acc);
    float acc2 = b2[j];
    #pragma unroll 8
    for (int k2 = 0; k2 < 64; ++k2) acc2 += __shfl(u1, k2) * w2[k2*64 + j];
    float o = acc2 + hr[j];
    if (do_relu) o = fmaxf(o, 0.f);
    out[(size_t)ru*HH + j] = o;
}

// ---------------- fused QKV projection ----------------
__global__ void k_qkv(const float* __restrict__ h,
                      const float* __restrict__ wq, const float* __restrict__ wk,
                      const float* __restrict__ wv,
                      const float* __restrict__ bq, const float* __restrict__ bk,
                      const float* __restrict__ bv,
                      float* __restrict__ q, float* __restrict__ k, float* __restrict__ v)
{
    int gid = blockIdx.x*blockDim.x + threadIdx.x;
    int r = gid >> 6; int j = gid & 63;
    if (r >= RR) return;
    int ru = __builtin_amdgcn_readfirstlane(r);
    const float* hr = h + (size_t)ru*HH;
    float aq = bq[j], ak = bk[j], av = bv[j];
    #pragma unroll 8
    for (int c = 0; c < 64; ++c) {
        float s = hr[c];
        aq += s*wq[c*64 + j];
        ak += s*wk[c*64 + j];
        av += s*wv[c*64 + j];
    }
    q[(size_t)ru*HH + j] = aq;
    k[(size_t)ru*HH + j] = ak;
    v[(size_t)ru*HH + j] = av;
}

// ---------------- temporal attention (T=12, per (b,n,head,s) thread) ------
__global__ void k_attn(const float* __restrict__ q, const float* __restrict__ k,
                       const float* __restrict__ v, float* __restrict__ o)
{
    int gid = blockIdx.x*blockDim.x + threadIdx.x;
    if (gid >= BB*NN*NHEADS*TT) return;
    int s    = gid % TT;
    int head = (gid/TT) % NHEADS;
    int n    = (gid/(TT*NHEADS)) % NN;
    int b    = gid/(TT*NHEADS*NN);

    float qv[HD];
    size_t qoff = ((size_t)(b*TT + s)*NN + n)*HH + head*HD;
    #pragma unroll
    for (int d = 0; d < HD; ++d) qv[d] = q[qoff + d];

    float sc[TT]; float mx = -1e30f;
    #pragma unroll
    for (int t = 0; t < TT; ++t) {
        size_t koff = ((size_t)(b*TT + t)*NN + n)*HH + head*HD;
        float a = 0.f;
        #pragma unroll
        for (int d = 0; d < HD; ++d) a += qv[d]*k[koff + d];
        a *= 0.35355339059327373f; // 1/sqrt(8)
        sc[t] = a; mx = fmaxf(mx, a);
    }
    float sum = 0.f;
    #pragma unroll
    for (int t = 0; t < TT; ++t) { sc[t] = __expf(sc[t]-mx); sum += sc[t]; }
    float inv = 1.0f/sum;
    float ov[HD];
    #pragma unroll
    for (int d = 0; d < HD; ++d) ov[d] = 0.f;
    #pragma unroll
    for (int t = 0; t < TT; ++t) {
        size_t voff = ((size_t)(b*TT + t)*NN + n)*HH + head*HD;
        float a = sc[t]*inv;
        #pragma unroll
        for (int d = 0; d < HD; ++d) ov[d] += a*v[voff + d];
    }
    #pragma unroll
    for (int d = 0; d < HD; ++d) o[qoff + d] = ov[d];
}

// ---------------- generic 64x64 row-GEMM: out = in @ w + b ----------------
__global__ void k_rowgemm64(const float* __restrict__ in, const float* __restrict__ w,
                            const float* __restrict__ b, float* __restrict__ out)
{
    int gid = blockIdx.x*blockDim.x + threadIdx.x;
    int r = gid >> 6; int j = gid & 63;
    if (r >= RR) return;
    int ru = __builtin_amdgcn_readfirstlane(r);
    const float* ir = in + (size_t)ru*HH;
    float acc = b[j];
    #pragma unroll 8
    for (int c = 0; c < 64; ++c) acc += ir[c]*w[c*64 + j];
    out[(size_t)ru*HH + j] = acc;
}

// ---------------- fused conv(T->HOR) + MLP head ----------------
__global__ void k_convmlp(const float* __restrict__ h, const float* __restrict__ x,
                          const float* __restrict__ cw, const float* __restrict__ cb,
                          const float* __restrict__ w1, const float* __restrict__ b1,
                          const float* __restrict__ w2, const float* __restrict__ b2,
                          float* __restrict__ out)
{
    int gid = blockIdx.x*blockDim.x + threadIdx.x;
    if (gid >= BB*HORZ*NN) return;
    int n   = gid % NN;
    int hor = (gid/NN) % HORZ;
    int b   = gid/(NN*HORZ);

    float cwv[TT];
    #pragma unroll
    for (int t = 0; t < TT; ++t) cwv[t] = cw[hor*TT + t];
    float cbv = cb[hor];

    float z[72];
    #pragma unroll
    for (int c = 0; c < 72; ++c) z[c] = cbv;
    for (int t = 0; t < TT; ++t) {
        const float* hrow = h + ((size_t)(b*TT + t)*NN + n)*HH;
        const float* xrow = x + ((size_t)(b*TT + t)*NN + n)*CC;
        float wv = cwv[t];
        #pragma unroll
        for (int c = 0; c < 64; ++c) z[c]    += hrow[c]*wv;
        #pragma unroll
        for (int c = 0; c < 8; ++c)  z[64+c] += xrow[c]*wv;
    }

    float hid[64];
    #pragma unroll
    for (int k2 = 0; k2 < 64; ++k2) hid[k2] = b1[k2];
    #pragma unroll 2
    for (int c = 0; c < 72; ++c) {
        float v = z[c];
        #pragma unroll
        for (int k2 = 0; k2 < 64; ++k2) hid[k2] += v*w1[c*64 + k2];
    }
    #pragma unroll
    for (int k2 = 0; k2 < 64; ++k2) hid[k2] = fmaxf(hid[k2], 0.f);

    float o[8];
    #pragma unroll
    for (int c2 = 0; c2 < 8; ++c2) o[c2] = b2[c2];
    #pragma unroll 8
    for (int k2 = 0; k2 < 64; ++k2) {
        float v = hid[k2];
        #pragma unroll
        for (int c2 = 0; c2 < 8; ++c2) o[c2] += v*w2[k2*8 + c2];
    }
    size_t ooff = ((size_t)(b*HORZ + hor)*NN + n)*CC;
    #pragma unroll
    for (int c2 = 0; c2 < 8; ++c2) out[ooff + c2] = o[c2];
}

extern "C" void kernel_launch(void* const* d_in, const int* in_sizes, int n_in,
                              void* d_out, int out_size, void* d_ws, size_t ws_size,
                              hipStream_t stream) {
    const float* x    = (const float*)d_in[0];
    const int*   eidx = (const int*)d_in[1];
    const float* up_w = (const float*)d_in[2];
    const float* up_b = (const float*)d_in[3];
    const float* sp_w[2][10];
    for (int p = 0; p < 2; ++p)
        for (int i = 0; i < 10; ++i)
            sp_w[p][i] = (const float*)d_in[4 + p*10 + i];
    const float* wq = (const float*)d_in[24];
    const float* wk = (const float*)d_in[25];
    const float* wv = (const float*)d_in[26];
    const float* wo = (const float*)d_in[27];
    const float* bq = (const float*)d_in[28];
    const float* bk = (const float*)d_in[29];
    const float* bv = (const float*)d_in[30];
    const float* bo = (const float*)d_in[31];
    const float* conv_w = (const float*)d_in[32];
    const float* conv_b = (const float*)d_in[33];
    const float* mlp_w1 = (const float*)d_in[34];
    const float* mlp_b1 = (const float*)d_in[35];
    const float* mlp_w2 = (const float*)d_in[36];
    const float* mlp_b2 = (const float*)d_in[37];
    float* out = (float*)d_out;

    const size_t BUF = (size_t)RR*HH;      // 6,144,000 floats
    float* A    = (float*)d_ws;            // h
    float* Bb   = A   + BUF;               // h2
    float* AGG  = Bb  + BUF;               // agg / K
    float* Vb   = AGG + BUF;               // V
    float* Ob   = Vb  + BUF;               // attn out
    float* PRE  = Ob  + BUF;               // per-node first-layer precompute
    int*   cnt      = (int*)(PRE + BUF);   // 2048
    int*   ofs_work = cnt + 2048;          // 2048
    int*   ssrc     = ofs_work + 2048;     // EE
    int*   stgt     = ssrc + EE;           // EE

    const int ROWGRID = (RR*64)/256;       // 24000 blocks of 256

    // ---- CSR build (cheap; same work every call) ----
    hipMemsetAsync(cnt, 0, 2048*sizeof(int), stream);
    k_hist<<<(EE+255)/256, 256, 0, stream>>>(eidx, cnt);
    k_scan<<<1, 256, 0, stream>>>(cnt, ofs_work);
    k_scatter<<<(EE+255)/256, 256, 0, stream>>>(eidx, ofs_work, ssrc, stgt);

    // 1. up-projection
    k_up<<<ROWGRID, 256, 0, stream>>>(x, up_w, up_b, A);

    // 2. spatial 1
    hipMemsetAsync(AGG, 0, BUF*sizeof(float), stream);
    k_pre<<<ROWGRID, 256, 0, stream>>>(A, sp_w[0][0], PRE);
    k_msg<<<BT*(EE/64), 64, 0, stream>>>(PRE, ssrc, stgt,
        sp_w[0][1], sp_w[0][2], sp_w[0][3], sp_w[0][4], sp_w[0][5], AGG);
    k_upd<<<ROWGRID, 256, 0, stream>>>(A, AGG,
        sp_w[0][6], sp_w[0][7], sp_w[0][8], sp_w[0][9], Bb, 1);

    // 3. temporal: QKV (Q->A, K->AGG, V->Vb), attn -> Ob, proj -> A
    k_qkv<<<ROWGRID, 256, 0, stream>>>(Bb, wq, wk, wv, bq, bk, bv, A, AGG, Vb);
    k_attn<<<(BB*NN*NHEADS*TT + 255)/256, 256, 0, stream>>>(A, AGG, Vb, Ob);
    k_rowgemm64<<<ROWGRID, 256, 0, stream>>>(Ob, wo, bo, A);

    // 4. spatial 2
    hipMemsetAsync(AGG, 0, BUF*sizeof(float), stream);
    k_pre<<<ROWGRID, 256, 0, stream>>>(A, sp_w[1][0], PRE);
    k_msg<<<BT*(EE/64), 64, 0, stream>>>(PRE, ssrc, stgt,
        sp_w[1][1], sp_w[1][2], sp_w[1][3], sp_w[1][4], sp_w[1][5], AGG);
    k_upd<<<ROWGRID, 256, 0, stream>>>(A, AGG,
        sp_w[1][6], sp_w[1][7], sp_w[1][8], sp_w[1][9], Bb, 1);

    // 5. conv + MLP head -> out
    k_convmlp<<<(BB*HORZ*NN + 255)/256, 256, 0, stream>>>(Bb, x,
        conv_w, conv_b, mlp_w1, mlp_b1, mlp_w2, mlp_b2, out);
}

// Round 3
// 889.691 us; speedup vs baseline: 12.4681x; 1.3736x over previous
//
#include <hip/hip_runtime.h>
#include <math.h>

#define BB 4
#define TT 12
#define NN 2000
#define CC 8
#define HH 64
#define EE 32000
#define NHEADS 8
#define HD 8
#define HORZ 12
#define BT (BB*TT)        // 48
#define RR (BT*NN)        // 96000 rows of H=64

using bf16x8 = __attribute__((ext_vector_type(8))) __bf16;
using f32x4  = __attribute__((ext_vector_type(4))) float;

__device__ __forceinline__ float sigmoidf_(float x){ return 1.0f/(1.0f+__expf(-x)); }
__device__ __forceinline__ float siluf_(float x){ return x/(1.0f+__expf(-x)); }

// ================= CSR build (edges sorted by tgt) =================
__global__ void k_hist(const int* __restrict__ eidx, int* __restrict__ cnt) {
    int e = blockIdx.x*blockDim.x + threadIdx.x;
    if (e < EE) atomicAdd(&cnt[eidx[EE + e]], 1);
}

__global__ __launch_bounds__(256) void k_scan(const int* __restrict__ cnt,
                                              int* __restrict__ ofs_work) {
    __shared__ int part[256];
    int tid = threadIdx.x;
    int local[8]; int s = 0;
    #pragma unroll
    for (int k = 0; k < 8; ++k) {
        int idx = tid*8 + k;
        int v = (idx < NN) ? cnt[idx] : 0;
        local[k] = s; s += v;
    }
    part[tid] = s; __syncthreads();
    for (int off = 1; off < 256; off <<= 1) {
        int v = part[tid];
        int u = (tid >= off) ? part[tid-off] : 0;
        __syncthreads();
        part[tid] = v + u;
        __syncthreads();
    }
    int excl = part[tid] - s;
    #pragma unroll
    for (int k = 0; k < 8; ++k) {
        int idx = tid*8 + k;
        if (idx < NN) ofs_work[idx] = excl + local[k];
    }
}

__global__ void k_scatter(const int* __restrict__ eidx, int* __restrict__ ofs_work,
                          int* __restrict__ ssrc, int* __restrict__ stgt) {
    int e = blockIdx.x*blockDim.x + threadIdx.x;
    if (e >= EE) return;
    int t = eidx[EE + e];
    int pos = atomicAdd(&ofs_work[t], 1);
    ssrc[pos] = eidx[e];
    stgt[pos] = t;
}

// ========== W2 -> bf16, transposed to B-fragment-friendly [n][k] ==========
__global__ void k_w2prep(const float* __restrict__ w2, __bf16* __restrict__ w2t) {
    int i = blockIdx.x*blockDim.x + threadIdx.x;  // 2048 = 64 n * 32 k
    if (i >= 2048) return;
    int n = i >> 5, k = i & 31;
    w2t[i] = (__bf16)w2[k*64 + n];
}

// ========== per-node precompute of first msg-MLP layer (4 rows/wave) ======
__global__ void k_pre(const float* __restrict__ h, const float* __restrict__ w1,
                      float* __restrict__ preW) {
    int gid = blockIdx.x*blockDim.x + threadIdx.x;
    int wv_ = gid >> 6; int j = gid & 63;
    int r0 = wv_*4;
    if (r0 >= RR) return;
    r0 = __builtin_amdgcn_readfirstlane(r0);
    const float* hr = h + (size_t)r0*HH;
    int base = (j < 32) ? j : (2048 + j - 32);
    float a0=0.f,a1=0.f,a2=0.f,a3=0.f;
    #pragma unroll 8
    for (int c = 0; c < 64; ++c) {
        float wc = w1[c*32 + base];
        a0 += hr[c]*wc; a1 += hr[HH+c]*wc; a2 += hr[2*HH+c]*wc; a3 += hr[3*HH+c]*wc;
    }
    preW[(size_t)r0*HH + j]        = a0;
    preW[(size_t)r0*HH + HH + j]   = a1;
    preW[(size_t)r0*HH + 2*HH + j] = a2;
    preW[(size_t)r0*HH + 3*HH + j] = a3;
}

// ========== message MLP (MFMA layer-2) + gate + segmented scatter =========
__global__ __launch_bounds__(64) void k_msg(
    const float* __restrict__ preW, const int* __restrict__ ssrc,
    const int* __restrict__ stgt,
    const float* __restrict__ b1,
    const __bf16* __restrict__ w2t, const float* __restrict__ b2,
    const float* __restrict__ gw, const float* __restrict__ gb,
    float* __restrict__ agg)
{
    const int EB = EE/64; // 500
    int eb = blockIdx.x % EB;
    int bt = blockIdx.x / EB;
    int t  = threadIdx.x;
    int l15 = t & 15, quad = t >> 4;

    union __align__(16) SM {
        float  cat[64][65];   // gather stage
        __bf16 ab [64][40];   // A-fragment staging (pad 40 -> 16B-aligned frag reads)
        float  msg[64][66];   // gated messages for the scan
    };
    __shared__ SM sm;

    int e0 = eb*64;
    int my_src = ssrc[e0 + t];
    int my_tgt = stgt[e0 + t];
    const float* pw = preW + (size_t)bt*NN*HH;

    // gather: edge e: lanes 0-31 take xiW[tgt][0:32], lanes 32-63 xjW[src][32:64]
    #pragma unroll 8
    for (int e = 0; e < 64; ++e) {
        int s = __shfl(my_src, e);
        int g = __shfl(my_tgt, e);
        int node = (t < 32) ? g : s;
        sm.cat[e][t] = pw[(size_t)node*HH + t];
    }
    __syncthreads();

    // layer 1 (factored): m1 = silu(xiW + xjW + b1), thread t = edge t
    float m1[32];
    #pragma unroll
    for (int k2 = 0; k2 < 32; ++k2)
        m1[k2] = siluf_(sm.cat[t][k2] + sm.cat[t][32+k2] + b1[k2]);
    __syncthreads();   // all cat reads done before aliasing

    // stage A-fragments: row = edge, 32 bf16 k's
    #pragma unroll
    for (int g4 = 0; g4 < 4; ++g4) {
        bf16x8 v;
        #pragma unroll
        for (int j = 0; j < 8; ++j) v[j] = (__bf16)m1[g4*8 + j];
        ((bf16x8*)&sm.ab[t][0])[g4] = v;
    }
    __syncthreads();

    // B fragments (W2^T bf16, [n][k]), bias/gate vectors
    bf16x8 bfr[4];
    float b2v[4], gwv[4];
    #pragma unroll
    for (int ni = 0; ni < 4; ++ni) {
        bfr[ni] = *(const bf16x8*)&w2t[(16*ni + l15)*32 + quad*8];
        b2v[ni] = b2[16*ni + l15];
        gwv[ni] = gw[16*ni + l15];
    }
    float gb0 = gb[0];

    // 64x64 = 4x4 tiles of 16x16, K=32 in one MFMA each
    f32x4 acc[4][4];
    #pragma unroll
    for (int mi = 0; mi < 4; ++mi) {
        bf16x8 af = *(const bf16x8*)&sm.ab[16*mi + l15][quad*8];
        #pragma unroll
        for (int ni = 0; ni < 4; ++ni) {
            f32x4 z = {0.f, 0.f, 0.f, 0.f};
            acc[mi][ni] = __builtin_amdgcn_mfma_f32_16x16x32_bf16(af, bfr[ni], z, 0, 0, 0);
        }
    }
    __syncthreads();  // ab frag reads done before aliasing msg

    // silu + gate (per-edge reduce across the 16 lanes of this quad) + stash
    #pragma unroll
    for (int mi = 0; mi < 4; ++mi) {
        #pragma unroll
        for (int ni = 0; ni < 4; ++ni) {
            #pragma unroll
            for (int rg = 0; rg < 4; ++rg)
                acc[mi][ni][rg] = siluf_(acc[mi][ni][rg] + b2v[ni]);
        }
        #pragma unroll
        for (int rg = 0; rg < 4; ++rg) {
            float p = acc[mi][0][rg]*gwv[0] + acc[mi][1][rg]*gwv[1]
                    + acc[mi][2][rg]*gwv[2] + acc[mi][3][rg]*gwv[3];
            p += __shfl_xor(p, 1); p += __shfl_xor(p, 2);
            p += __shfl_xor(p, 4); p += __shfl_xor(p, 8);
            float g = sigmoidf_(p + gb0);
            int er = 16*mi + 4*quad + rg;   // C layout: row = quad*4+reg
            #pragma unroll
            for (int ni = 0; ni < 4; ++ni)
                sm.msg[er][16*ni + l15] = g * acc[mi][ni][rg];
        }
    }
    __syncthreads();

    // segmented reduction: lane t = feature, scan edges sorted by tgt
    float* ab_ = agg + (size_t)bt*NN*HH;
    float a = 0.f;
    int prev = __shfl(my_tgt, 0);
    for (int e = 0; e < 64; ++e) {
        int te = __shfl(my_tgt, e);        // wave-uniform
        if (te != prev) {
            atomicAdd(&ab_[(size_t)prev*HH + t], a);
            a = 0.f; prev = te;
        }
        a += sm.msg[e][t];
    }
    atomicAdd(&ab_[(size_t)prev*HH + t], a);
}

// ---------------- up-projection (4 rows/wave) ----------------
__global__ void k_up(const float* __restrict__ x, const float* __restrict__ w,
                     const float* __restrict__ b, float* __restrict__ h) {
    int gid = blockIdx.x*blockDim.x + threadIdx.x;
    int wv_ = gid >> 6; int j = gid & 63;
    int r0 = wv_*4;
    if (r0 >= RR) return;
    r0 = __builtin_amdgcn_readfirstlane(r0);
    const float* xr = x + (size_t)r0*CC;
    float bj = b[j];
    float a0=bj,a1=bj,a2=bj,a3=bj;
    #pragma unroll
    for (int c = 0; c < CC; ++c) {
        float wc = w[c*HH + j];
        a0 += xr[c]*wc; a1 += xr[CC+c]*wc; a2 += xr[2*CC+c]*wc; a3 += xr[3*CC+c]*wc;
    }
    h[(size_t)r0*HH + j]        = fmaxf(a0, 0.f);
    h[(size_t)r0*HH + HH + j]   = fmaxf(a1, 0.f);
    h[(size_t)r0*HH + 2*HH + j] = fmaxf(a2, 0.f);
    h[(size_t)r0*HH + 3*HH + j] = fmaxf(a3, 0.f);
}

// ---------------- spatial update (4 rows/wave) ----------------
__global__ void k_upd(const float* __restrict__ h, const float* __restrict__ agg,
                      const float* __restrict__ w1, const float* __restrict__ b1,
                      const float* __restrict__ w2, const float* __restrict__ b2,
                      float* __restrict__ out, int do_relu)
{
    int gid = blockIdx.x*blockDim.x + threadIdx.x;
    int wv_ = gid >> 6; int j = gid & 63;
    int r0 = wv_*4;
    if (r0 >= RR) return;
    r0 = __builtin_amdgcn_readfirstlane(r0);
    const float* ar = agg + (size_t)r0*HH;
    const float* hr = h   + (size_t)r0*HH;
    float bj = b1[j];
    float a0=bj,a1=bj,a2=bj,a3=bj;
    #pragma unroll 8
    for (int c = 0; c < 64; ++c) {
        float wv = w1[c*64 + j];
        a0 += ar[c]*wv; a1 += ar[HH+c]*wv; a2 += ar[2*HH+c]*wv; a3 += ar[3*HH+c]*wv;
    }
    #pragma unroll 8
    for (int c = 0; c < 64; ++c) {
        float wv = w1[(64+c)*64 + j];
        a0 += hr[c]*wv; a1 += hr[HH+c]*wv; a2 += hr[2*HH+c]*wv; a3 += hr[3*HH+c]*wv;
    }
    float u0=siluf_(a0), u1=siluf_(a1), u2=siluf_(a2), u3=siluf_(a3);
    float b2j = b2[j];
    float c0=b2j,c1=b2j,c2=b2j,c3=b2j;
    #pragma unroll 8
    for (int k2 = 0; k2 < 64; ++k2) {
        float wv = w2[k2*64 + j];
        c0 += __shfl(u0,k2)*wv; c1 += __shfl(u1,k2)*wv;
        c2 += __shfl(u2,k2)*wv; c3 += __shfl(u3,k2)*wv;
    }
    float o0 = c0 + hr[j],        o1 = c1 + hr[HH+j];
    float o2 = c2 + hr[2*HH+j],   o3 = c3 + hr[3*HH+j];
    if (do_relu) { o0=fmaxf(o0,0.f); o1=fmaxf(o1,0.f); o2=fmaxf(o2,0.f); o3=fmaxf(o3,0.f); }
    out[(size_t)r0*HH + j]        = o0;
    out[(size_t)r0*HH + HH + j]   = o1;
    out[(size_t)r0*HH + 2*HH + j] = o2;
    out[(size_t)r0*HH + 3*HH + j] = o3;
}

// ---------------- fused QKV projection (4 rows/wave) ----------------
__global__ void k_qkv(const float* __restrict__ h,
                      const float* __restrict__ wq, const float* __restrict__ wk,
                      const float* __restrict__ wv,
                      const float* __restrict__ bq, const float* __restrict__ bk,
                      const float* __restrict__ bv,
                      float* __restrict__ q, float* __restrict__ k, float* __restrict__ v)
{
    int gid = blockIdx.x*blockDim.x + threadIdx.x;
    int wv_ = gid >> 6; int j = gid & 63;
    int r0 = wv_*4;
    if (r0 >= RR) return;
    r0 = __builtin_amdgcn_readfirstlane(r0);
    const float* hr = h + (size_t)r0*HH;
    float q0=bq[j],q1=q0,q2=q0,q3=q0;
    float k0=bk[j],k1=k0,k2v=k0,k3=k0;
    float v0=bv[j],v1=v0,v2=v0,v3=v0;
    #pragma unroll 4
    for (int c = 0; c < 64; ++c) {
        float wqc = wq[c*64 + j], wkc = wk[c*64 + j], wvc = wv[c*64 + j];
        float h0 = hr[c], h1 = hr[HH+c], h2 = hr[2*HH+c], h3 = hr[3*HH+c];
        q0 += h0*wqc; q1 += h1*wqc; q2 += h2*wqc; q3 += h3*wqc;
        k0 += h0*wkc; k1 += h1*wkc; k2v += h2*wkc; k3 += h3*wkc;
        v0 += h0*wvc; v1 += h1*wvc; v2 += h2*wvc; v3 += h3*wvc;
    }
    size_t o = (size_t)r0*HH + j;
    q[o]=q0; q[o+HH]=q1; q[o+2*HH]=q2; q[o+3*HH]=q3;
    k[o]=k0; k[o+HH]=k1; k[o+2*HH]=k2v; k[o+3*HH]=k3;
    v[o]=v0; v[o+HH]=v1; v[o+2*HH]=v2; v[o+3*HH]=v3;
}

// ---------------- temporal attention (T=12, per (b,n,head,s) thread) ------
__global__ void k_attn(const float* __restrict__ q, const float* __restrict__ k,
                       const float* __restrict__ v, float* __restrict__ o)
{
    int gid = blockIdx.x*blockDim.x + threadIdx.x;
    if (gid >= BB*NN*NHEADS*TT) return;
    int s    = gid % TT;
    int head = (gid/TT) % NHEADS;
    int n    = (gid/(TT*NHEADS)) % NN;
    int b    = gid/(TT*NHEADS*NN);

    float qv[HD];
    size_t qoff = ((size_t)(b*TT + s)*NN + n)*HH + head*HD;
    #pragma unroll
    for (int d = 0; d < HD; ++d) qv[d] = q[qoff + d];

    float sc[TT]; float mx = -1e30f;
    #pragma unroll
    for (int t = 0; t < TT; ++t) {
        size_t koff = ((size_t)(b*TT + t)*NN + n)*HH + head*HD;
        float a = 0.f;
        #pragma unroll
        for (int d = 0; d < HD; ++d) a += qv[d]*k[koff + d];
        a *= 0.35355339059327373f;
        sc[t] = a; mx = fmaxf(mx, a);
    }
    float sum = 0.f;
    #pragma unroll
    for (int t = 0; t < TT; ++t) { sc[t] = __expf(sc[t]-mx); sum += sc[t]; }
    float inv = 1.0f/sum;
    float ov[HD];
    #pragma unroll
    for (int d = 0; d < HD; ++d) ov[d] = 0.f;
    #pragma unroll
    for (int t = 0; t < TT; ++t) {
        size_t voff = ((size_t)(b*TT + t)*NN + n)*HH + head*HD;
        float a = sc[t]*inv;
        #pragma unroll
        for (int d = 0; d < HD; ++d) ov[d] += a*v[voff + d];
    }
    #pragma unroll
    for (int d = 0; d < HD; ++d) o[qoff + d] = ov[d];
}

// ---------------- 64x64 row-GEMM (4 rows/wave) ----------------
__global__ void k_rowgemm64(const float* __restrict__ in, const float* __restrict__ w,
                            const float* __restrict__ b, float* __restrict__ out)
{
    int gid = blockIdx.x*blockDim.x + threadIdx.x;
    int wv_ = gid >> 6; int j = gid & 63;
    int r0 = wv_*4;
    if (r0 >= RR) return;
    r0 = __builtin_amdgcn_readfirstlane(r0);
    const float* ir = in + (size_t)r0*HH;
    float bj = b[j];
    float a0=bj,a1=bj,a2=bj,a3=bj;
    #pragma unroll 8
    for (int c = 0; c < 64; ++c) {
        float wc = w[c*64 + j];
        a0 += ir[c]*wc; a1 += ir[HH+c]*wc; a2 += ir[2*HH+c]*wc; a3 += ir[3*HH+c]*wc;
    }
    out[(size_t)r0*HH + j]        = a0;
    out[(size_t)r0*HH + HH + j]   = a1;
    out[(size_t)r0*HH + 2*HH + j] = a2;
    out[(size_t)r0*HH + 3*HH + j] = a3;
}

// ---------------- fused conv(T->HOR) + MLP head ----------------
__global__ void k_convmlp(const float* __restrict__ h, const float* __restrict__ x,
                          const float* __restrict__ cw, const float* __restrict__ cb,
                          const float* __restrict__ w1, const float* __restrict__ b1,
                          const float* __restrict__ w2, const float* __restrict__ b2,
                          float* __restrict__ out)
{
    int gid = blockIdx.x*blockDim.x + threadIdx.x;
    if (gid >= BB*HORZ*NN) return;
    int n   = gid % NN;
    int hor = (gid/NN) % HORZ;
    int b   = gid/(NN*HORZ);

    float cwv[TT];
    #pragma unroll
    for (int t = 0; t < TT; ++t) cwv[t] = cw[hor*TT + t];
    float cbv = cb[hor];

    float z[72];
    #pragma unroll
    for (int c = 0; c < 72; ++c) z[c] = cbv;
    for (int t = 0; t < TT; ++t) {
        const float* hrow = h + ((size_t)(b*TT + t)*NN + n)*HH;
        const float* xrow = x + ((size_t)(b*TT + t)*NN + n)*CC;
        float wv = cwv[t];
        #pragma unroll
        for (int c = 0; c < 64; ++c) z[c]    += hrow[c]*wv;
        #pragma unroll
        for (int c = 0; c < 8; ++c)  z[64+c] += xrow[c]*wv;
    }

    float hid[64];
    #pragma unroll
    for (int k2 = 0; k2 < 64; ++k2) hid[k2] = b1[k2];
    #pragma unroll 2
    for (int c = 0; c < 72; ++c) {
        float v = z[c];
        #pragma unroll
        for (int k2 = 0; k2 < 64; ++k2) hid[k2] += v*w1[c*64 + k2];
    }
    #pragma unroll
    for (int k2 = 0; k2 < 64; ++k2) hid[k2] = fmaxf(hid[k2], 0.f);

    float o[8];
    #pragma unroll
    for (int c2 = 0; c2 < 8; ++c2) o[c2] = b2[c2];
    #pragma unroll 8
    for (int k2 = 0; k2 < 64; ++k2) {
        float v = hid[k2];
        #pragma unroll
        for (int c2 = 0; c2 < 8; ++c2) o[c2] += v*w2[k2*8 + c2];
    }
    size_t ooff = ((size_t)(b*HORZ + hor)*NN + n)*CC;
    #pragma unroll
    for (int c2 = 0; c2 < 8; ++c2) out[ooff + c2] = o[c2];
}

extern "C" void kernel_launch(void* const* d_in, const int* in_sizes, int n_in,
                              void* d_out, int out_size, void* d_ws, size_t ws_size,
                              hipStream_t stream) {
    const float* x    = (const float*)d_in[0];
    const int*   eidx = (const int*)d_in[1];
    const float* up_w = (const float*)d_in[2];
    const float* up_b = (const float*)d_in[3];
    const float* sp_w[2][10];
    for (int p = 0; p < 2; ++p)
        for (int i = 0; i < 10; ++i)
            sp_w[p][i] = (const float*)d_in[4 + p*10 + i];
    const float* wq = (const float*)d_in[24];
    const float* wk = (const float*)d_in[25];
    const float* wv = (const float*)d_in[26];
    const float* wo = (const float*)d_in[27];
    const float* bq = (const float*)d_in[28];
    const float* bk = (const float*)d_in[29];
    const float* bv = (const float*)d_in[30];
    const float* bo = (const float*)d_in[31];
    const float* conv_w = (const float*)d_in[32];
    const float* conv_b = (const float*)d_in[33];
    const float* mlp_w1 = (const float*)d_in[34];
    const float* mlp_b1 = (const float*)d_in[35];
    const float* mlp_w2 = (const float*)d_in[36];
    const float* mlp_b2 = (const float*)d_in[37];
    float* out = (float*)d_out;

    const size_t BUF = (size_t)RR*HH;      // 6,144,000 floats
    float* A    = (float*)d_ws;            // h
    float* Bb   = A   + BUF;               // h2
    float* AGG  = Bb  + BUF;               // agg / K
    float* Vb   = AGG + BUF;               // V
    float* Ob   = Vb  + BUF;               // attn out
    float* PRE  = Ob  + BUF;               // per-node first-layer precompute
    int*   cnt      = (int*)(PRE + BUF);   // 2048
    int*   ofs_work = cnt + 2048;          // 2048
    int*   ssrc     = ofs_work + 2048;     // EE
    int*   stgt     = ssrc + EE;           // EE
    __bf16* w2t0    = (__bf16*)(stgt + EE);// 2048 bf16 (16B-aligned)
    __bf16* w2t1    = w2t0 + 2048;

    const int G4 = RR/16;                  // 6000 blocks of 256 (4 rows/wave)

    // ---- CSR build + weight prep ----
    hipMemsetAsync(cnt, 0, 2048*sizeof(int), stream);
    k_hist<<<(EE+255)/256, 256, 0, stream>>>(eidx, cnt);
    k_w2prep<<<8, 256, 0, stream>>>(sp_w[0][2], w2t0);
    k_w2prep<<<8, 256, 0, stream>>>(sp_w[1][2], w2t1);
    k_scan<<<1, 256, 0, stream>>>(cnt, ofs_work);
    k_scatter<<<(EE+255)/256, 256, 0, stream>>>(eidx, ofs_work, ssrc, stgt);

    // 1. up-projection
    k_up<<<G4, 256, 0, stream>>>(x, up_w, up_b, A);

    // 2. spatial 1
    hipMemsetAsync(AGG, 0, BUF*sizeof(float), stream);
    k_pre<<<G4, 256, 0, stream>>>(A, sp_w[0][0], PRE);
    k_msg<<<BT*(EE/64), 64, 0, stream>>>(PRE, ssrc, stgt,
        sp_w[0][1], w2t0, sp_w[0][3], sp_w[0][4], sp_w[0][5], AGG);
    k_upd<<<G4, 256, 0, stream>>>(A, AGG,
        sp_w[0][6], sp_w[0][7], sp_w[0][8], sp_w[0][9], Bb, 1);

    // 3. temporal: QKV (Q->A, K->AGG, V->Vb), attn -> Ob, proj -> A
    k_qkv<<<G4, 256, 0, stream>>>(Bb, wq, wk, wv, bq, bk, bv, A, AGG, Vb);
    k_attn<<<(BB*NN*NHEADS*TT + 255)/256, 256, 0, stream>>>(A, AGG, Vb, Ob);
    k_rowgemm64<<<G4, 256, 0, stream>>>(Ob, wo, bo, A);

    // 4. spatial 2
    hipMemsetAsync(AGG, 0, BUF*sizeof(float), stream);
    k_pre<<<G4, 256, 0, stream>>>(A, sp_w[1][0], PRE);
    k_msg<<<BT*(EE/64), 64, 0, stream>>>(PRE, ssrc, stgt,
        sp_w[1][1], w2t1, sp_w[1][3], sp_w[1][4], sp_w[1][5], AGG);
    k_upd<<<G4, 256, 0, stream>>>(A, AGG,
        sp_w[1][6], sp_w[1][7], sp_w[1][8], sp_w[1][9], Bb, 1);

    // 5. conv + MLP head -> out
    k_convmlp<<<(BB*HORZ*NN + 255)/256, 256, 0, stream>>>(Bb, x,
        conv_w, conv_b, mlp_w1, mlp_b1, mlp_w2, mlp_b2, out);
}

// Round 4
// 724.287 us; speedup vs baseline: 15.3154x; 1.2284x over previous
//
#include <hip/hip_runtime.h>
#include <math.h>

#define BB 4
#define TT 12
#define NN 2000
#define CC 8
#define HH 64
#define EE 32000
#define NHEADS 8
#define HD 8
#define HORZ 12
#define BT (BB*TT)        // 48
#define RR (BT*NN)        // 96000 rows of H=64

using bf16x8 = __attribute__((ext_vector_type(8))) __bf16;
using f16x8  = __attribute__((ext_vector_type(8))) _Float16;
using f16x4  = __attribute__((ext_vector_type(4))) _Float16;
using f32x4  = __attribute__((ext_vector_type(4))) float;

__device__ __forceinline__ float sigmoidf_(float x){ return 1.0f/(1.0f+__expf(-x)); }
__device__ __forceinline__ float siluf_(float x){ return x/(1.0f+__expf(-x)); }

// ================= CSR build (edges sorted by tgt) =================
__global__ void k_hist(const int* __restrict__ eidx, int* __restrict__ cnt) {
    int e = blockIdx.x*blockDim.x + threadIdx.x;
    if (e < EE) atomicAdd(&cnt[eidx[EE + e]], 1);
}

__global__ __launch_bounds__(256) void k_scan(const int* __restrict__ cnt,
                                              int* __restrict__ ofs_work) {
    __shared__ int part[256];
    int tid = threadIdx.x;
    int local[8]; int s = 0;
    #pragma unroll
    for (int k = 0; k < 8; ++k) {
        int idx = tid*8 + k;
        int v = (idx < NN) ? cnt[idx] : 0;
        local[k] = s; s += v;
    }
    part[tid] = s; __syncthreads();
    for (int off = 1; off < 256; off <<= 1) {
        int v = part[tid];
        int u = (tid >= off) ? part[tid-off] : 0;
        __syncthreads();
        part[tid] = v + u;
        __syncthreads();
    }
    int excl = part[tid] - s;
    #pragma unroll
    for (int k = 0; k < 8; ++k) {
        int idx = tid*8 + k;
        if (idx < NN) ofs_work[idx] = excl + local[k];
    }
}

__global__ void k_scatter(const int* __restrict__ eidx, int* __restrict__ ofs_work,
                          int* __restrict__ ssrc, int* __restrict__ stgt) {
    int e = blockIdx.x*blockDim.x + threadIdx.x;
    if (e >= EE) return;
    int t = eidx[EE + e];
    int pos = atomicAdd(&ofs_work[t], 1);
    ssrc[pos] = eidx[e];
    stgt[pos] = t;
}

// ========== W2 -> bf16, transposed to B-fragment-friendly [n][k] ==========
__global__ void k_w2prep(const float* __restrict__ w2, __bf16* __restrict__ w2t) {
    int i = blockIdx.x*blockDim.x + threadIdx.x;  // 2048 = 64 n * 32 k
    if (i >= 2048) return;
    int n = i >> 5, k = i & 31;
    w2t[i] = (__bf16)w2[k*64 + n];
}

// ========== per-node precompute of first msg-MLP layer (bf16 out) ======
// preB[row][j]: j<32 -> (h_row @ W1_top)[j] (xi part), j>=32 -> (h_row @ W1_bot)[j-32]
__global__ void k_pre(const float* __restrict__ h, const float* __restrict__ w1,
                      __bf16* __restrict__ preB) {
    int gid = blockIdx.x*blockDim.x + threadIdx.x;
    int wv_ = gid >> 6; int j = gid & 63;
    int r0 = wv_*4;
    if (r0 >= RR) return;
    r0 = __builtin_amdgcn_readfirstlane(r0);
    const float* hr = h + (size_t)r0*HH;
    int base = (j < 32) ? j : (2048 + j - 32);
    float a0=0.f,a1=0.f,a2=0.f,a3=0.f;
    #pragma unroll 8
    for (int c = 0; c < 64; ++c) {
        float wc = w1[c*32 + base];
        a0 += hr[c]*wc; a1 += hr[HH+c]*wc; a2 += hr[2*HH+c]*wc; a3 += hr[3*HH+c]*wc;
    }
    preB[(size_t)r0*HH + j]        = (__bf16)a0;
    preB[(size_t)r0*HH + HH + j]   = (__bf16)a1;
    preB[(size_t)r0*HH + 2*HH + j] = (__bf16)a2;
    preB[(size_t)r0*HH + 3*HH + j] = (__bf16)a3;
}

// ========== message MLP + gate + indicator-MFMA segmented aggregation =====
__global__ __launch_bounds__(64) void k_msg(
    const __bf16* __restrict__ preB, const int* __restrict__ ssrc,
    const int* __restrict__ stgt,
    const float* __restrict__ b1,
    const __bf16* __restrict__ w2t, const float* __restrict__ b2,
    const float* __restrict__ gw, const float* __restrict__ gb,
    float* __restrict__ agg)
{
    const int EB = EE/64; // 500
    int eb = blockIdx.x % EB;
    int bt = blockIdx.x / EB;
    int t  = threadIdx.x;
    int l15 = t & 15, quad = t >> 4;

    union __align__(16) SM {
        __bf16   ab[64][40];     // layer-2 A-frag staging (stride 40 -> conflict-free b128)
        _Float16 bs[8][64][8];   // agg B-frag staging: [chunk*4+ni][lane][j]
    };
    __shared__ SM sm;
    __shared__ int segTgt[64];

    int e0 = eb*64;
    int my_src = ssrc[e0 + t];
    int my_tgt = stgt[e0 + t];

    // ---- segment ids within window (edges sorted by tgt) ----
    int prevt = __shfl(my_tgt, (t + 63) & 63);
    bool bnd = (t == 0) || (prevt != my_tgt);
    unsigned long long bm = __ballot(bnd);
    int seg = __builtin_amdgcn_mbcnt_hi((unsigned)(bm >> 32),
              __builtin_amdgcn_mbcnt_lo((unsigned)bm, 0u));
    int nseg = __popcll(bm);
    if (bnd) segTgt[seg] = my_tgt;

    // ---- direct register gather + factored layer 1 (lane t = edge e0+t) ----
    const __bf16* basep = preB + (size_t)bt*NN*HH;
    const __bf16* rT = basep + (size_t)my_tgt*HH;        // xi part: cols 0..31
    const __bf16* rS = basep + (size_t)my_src*HH + 32;   // xj part: cols 32..63
    bf16x8 xi[4], xj[4];
    #pragma unroll
    for (int g4 = 0; g4 < 4; ++g4) {
        xi[g4] = *(const bf16x8*)&rT[8*g4];
        xj[g4] = *(const bf16x8*)&rS[8*g4];
    }
    #pragma unroll
    for (int g4 = 0; g4 < 4; ++g4) {
        bf16x8 v;
        #pragma unroll
        for (int u = 0; u < 8; ++u) {
            float m = (float)xi[g4][u] + (float)xj[g4][u] + b1[8*g4 + u];
            v[u] = (__bf16)siluf_(m);
        }
        ((bf16x8*)&sm.ab[t][0])[g4] = v;
    }

    // B fragments of W2^T (bf16, [n][k]) + bias/gate vectors
    bf16x8 bfr[4];
    float b2v[4], gwv[4];
    #pragma unroll
    for (int ni = 0; ni < 4; ++ni) {
        bfr[ni] = *(const bf16x8*)&w2t[(16*ni + l15)*32 + quad*8];
        b2v[ni] = b2[16*ni + l15];
        gwv[ni] = gw[16*ni + l15];
    }
    float gb0 = gb[0];

    __syncthreads();  // ab + segTgt visible

    // ---- layer 2: 64x64 = 4x4 tiles, K=32 one MFMA each ----
    f32x4 acc[4][4];
    #pragma unroll
    for (int mi = 0; mi < 4; ++mi) {
        bf16x8 af = *(const bf16x8*)&sm.ab[16*mi + l15][quad*8];
        #pragma unroll
        for (int ni = 0; ni < 4; ++ni) {
            f32x4 z = {0.f, 0.f, 0.f, 0.f};
            acc[mi][ni] = __builtin_amdgcn_mfma_f32_16x16x32_bf16(af, bfr[ni], z, 0, 0, 0);
        }
    }
    __syncthreads();  // ab frag reads done; union region free for bs

    // ---- epilogue: silu + gate, stash P = g*m2 in B-frag layout (f16) ----
    #pragma unroll
    for (int mi = 0; mi < 4; ++mi) {
        float sv[4][4]; // [ni][rg]
        #pragma unroll
        for (int ni = 0; ni < 4; ++ni)
            #pragma unroll
            for (int rg = 0; rg < 4; ++rg)
                sv[ni][rg] = siluf_(acc[mi][ni][rg] + b2v[ni]);
        float gg[4];
        #pragma unroll
        for (int rg = 0; rg < 4; ++rg) {
            float p = sv[0][rg]*gwv[0] + sv[1][rg]*gwv[1]
                    + sv[2][rg]*gwv[2] + sv[3][rg]*gwv[3];
            p += __shfl_xor(p, 1); p += __shfl_xor(p, 2);
            p += __shfl_xor(p, 4); p += __shfl_xor(p, 8);
            gg[rg] = sigmoidf_(p + gb0);
        }
        // write: value (er=16mi+4quad+rg, col=16ni+l15) -> bs[chunk*4+ni][16*qb+l15][j]
        int c  = mi >> 1;
        int qb = 2*(mi & 1) + (quad >> 1);
        int j0 = 4*(quad & 1);
        #pragma unroll
        for (int ni = 0; ni < 4; ++ni) {
            f16x4 pk;
            #pragma unroll
            for (int rg = 0; rg < 4; ++rg) pk[rg] = (_Float16)(sv[ni][rg]*gg[rg]);
            *(f16x4*)&sm.bs[c*4 + ni][16*qb + l15][j0] = pk;
        }
    }
    __syncthreads();  // bs visible

    // ---- indicator-MFMA segmented aggregation ----
    f16x8 bfrag[2][4];
    #pragma unroll
    for (int c = 0; c < 2; ++c)
        #pragma unroll
        for (int ni = 0; ni < 4; ++ni)
            bfrag[c][ni] = *(const f16x8*)&sm.bs[c*4 + ni][t][0];

    float* ap = agg + (size_t)bt*NN*HH;
    for (int g0 = 0; g0 < nseg; g0 += 16) {
        f16x8 ind[2];
        #pragma unroll
        for (int c = 0; c < 2; ++c) {
            #pragma unroll
            for (int j = 0; j < 8; ++j) {
                int sj = __shfl(seg, 32*c + 8*quad + j);
                ind[c][j] = (sj == g0 + l15) ? (_Float16)1.0f : (_Float16)0.0f;
            }
        }
        f32x4 av[4];
        #pragma unroll
        for (int ni = 0; ni < 4; ++ni) {
            f32x4 z = {0.f, 0.f, 0.f, 0.f};
            av[ni] = __builtin_amdgcn_mfma_f32_16x16x32_f16(ind[0], bfrag[0][ni], z, 0, 0, 0);
            av[ni] = __builtin_amdgcn_mfma_f32_16x16x32_f16(ind[1], bfrag[1][ni], av[ni], 0, 0, 0);
        }
        #pragma unroll
        for (int rg = 0; rg < 4; ++rg) {
            int s = g0 + 4*quad + rg;   // C layout: row = quad*4 + reg
            if (s < nseg) {
                int tn = segTgt[s];
                #pragma unroll
                for (int ni = 0; ni < 4; ++ni)
                    atomicAdd(&ap[(size_t)tn*HH + 16*ni + l15], av[ni][rg]);
            }
        }
    }
}

// ---------------- up-projection (4 rows/wave) ----------------
__global__ void k_up(const float* __restrict__ x, const float* __restrict__ w,
                     const float* __restrict__ b, float* __restrict__ h) {
    int gid = blockIdx.x*blockDim.x + threadIdx.x;
    int wv_ = gid >> 6; int j = gid & 63;
    int r0 = wv_*4;
    if (r0 >= RR) return;
    r0 = __builtin_amdgcn_readfirstlane(r0);
    const float* xr = x + (size_t)r0*CC;
    float bj = b[j];
    float a0=bj,a1=bj,a2=bj,a3=bj;
    #pragma unroll
    for (int c = 0; c < CC; ++c) {
        float wc = w[c*HH + j];
        a0 += xr[c]*wc; a1 += xr[CC+c]*wc; a2 += xr[2*CC+c]*wc; a3 += xr[3*CC+c]*wc;
    }
    h[(size_t)r0*HH + j]        = fmaxf(a0, 0.f);
    h[(size_t)r0*HH + HH + j]   = fmaxf(a1, 0.f);
    h[(size_t)r0*HH + 2*HH + j] = fmaxf(a2, 0.f);
    h[(size_t)r0*HH + 3*HH + j] = fmaxf(a3, 0.f);
}

// ---------------- spatial update (4 rows/wave) ----------------
__global__ void k_upd(const float* __restrict__ h, const float* __restrict__ agg,
                      const float* __restrict__ w1, const float* __restrict__ b1,
                      const float* __restrict__ w2, const float* __restrict__ b2,
                      float* __restrict__ out, int do_relu)
{
    int gid = blockIdx.x*blockDim.x + threadIdx.x;
    int wv_ = gid >> 6; int j = gid & 63;
    int r0 = wv_*4;
    if (r0 >= RR) return;
    r0 = __builtin_amdgcn_readfirstlane(r0);
    const float* ar = agg + (size_t)r0*HH;
    const float* hr = h   + (size_t)r0*HH;
    float bj = b1[j];
    float a0=bj,a1=bj,a2=bj,a3=bj;
    #pragma unroll 8
    for (int c = 0; c < 64; ++c) {
        float wv = w1[c*64 + j];
        a0 += ar[c]*wv; a1 += ar[HH+c]*wv; a2 += ar[2*HH+c]*wv; a3 += ar[3*HH+c]*wv;
    }
    #pragma unroll 8
    for (int c = 0; c < 64; ++c) {
        float wv = w1[(64+c)*64 + j];
        a0 += hr[c]*wv; a1 += hr[HH+c]*wv; a2 += hr[2*HH+c]*wv; a3 += hr[3*HH+c]*wv;
    }
    float u0=siluf_(a0), u1=siluf_(a1), u2=siluf_(a2), u3=siluf_(a3);
    float b2j = b2[j];
    float c0=b2j,c1=b2j,c2=b2j,c3=b2j;
    #pragma unroll 8
    for (int k2 = 0; k2 < 64; ++k2) {
        float wv = w2[k2*64 + j];
        c0 += __shfl(u0,k2)*wv; c1 += __shfl(u1,k2)*wv;
        c2 += __shfl(u2,k2)*wv; c3 += __shfl(u3,k2)*wv;
    }
    float o0 = c0 + hr[j],        o1 = c1 + hr[HH+j];
    float o2 = c2 + hr[2*HH+j],   o3 = c3 + hr[3*HH+j];
    if (do_relu) { o0=fmaxf(o0,0.f); o1=fmaxf(o1,0.f); o2=fmaxf(o2,0.f); o3=fmaxf(o3,0.f); }
    out[(size_t)r0*HH + j]        = o0;
    out[(size_t)r0*HH + HH + j]   = o1;
    out[(size_t)r0*HH + 2*HH + j] = o2;
    out[(size_t)r0*HH + 3*HH + j] = o3;
}

// ---------------- fused QKV projection (4 rows/wave) ----------------
__global__ void k_qkv(const float* __restrict__ h,
                      const float* __restrict__ wq, const float* __restrict__ wk,
                      const float* __restrict__ wv,
                      const float* __restrict__ bq, const float* __restrict__ bk,
                      const float* __restrict__ bv,
                      float* __restrict__ q, float* __restrict__ k, float* __restrict__ v)
{
    int gid = blockIdx.x*blockDim.x + threadIdx.x;
    int wv_ = gid >> 6; int j = gid & 63;
    int r0 = wv_*4;
    if (r0 >= RR) return;
    r0 = __builtin_amdgcn_readfirstlane(r0);
    const float* hr = h + (size_t)r0*HH;
    float q0=bq[j],q1=q0,q2=q0,q3=q0;
    float k0=bk[j],k1=k0,k2v=k0,k3=k0;
    float v0=bv[j],v1=v0,v2=v0,v3=v0;
    #pragma unroll 4
    for (int c = 0; c < 64; ++c) {
        float wqc = wq[c*64 + j], wkc = wk[c*64 + j], wvc = wv[c*64 + j];
        float h0 = hr[c], h1 = hr[HH+c], h2 = hr[2*HH+c], h3 = hr[3*HH+c];
        q0 += h0*wqc; q1 += h1*wqc; q2 += h2*wqc; q3 += h3*wqc;
        k0 += h0*wkc; k1 += h1*wkc; k2v += h2*wkc; k3 += h3*wkc;
        v0 += h0*wvc; v1 += h1*wvc; v2 += h2*wvc; v3 += h3*wvc;
    }
    size_t o = (size_t)r0*HH + j;
    q[o]=q0; q[o+HH]=q1; q[o+2*HH]=q2; q[o+3*HH]=q3;
    k[o]=k0; k[o+HH]=k1; k[o+2*HH]=k2v; k[o+3*HH]=k3;
    v[o]=v0; v[o+HH]=v1; v[o+2*HH]=v2; v[o+3*HH]=v3;
}

// ---------------- temporal attention (T=12, per (b,n,head,s) thread) ------
__global__ void k_attn(const float* __restrict__ q, const float* __restrict__ k,
                       const float* __restrict__ v, float* __restrict__ o)
{
    int gid = blockIdx.x*blockDim.x + threadIdx.x;
    if (gid >= BB*NN*NHEADS*TT) return;
    int s    = gid % TT;
    int head = (gid/TT) % NHEADS;
    int n    = (gid/(TT*NHEADS)) % NN;
    int b    = gid/(TT*NHEADS*NN);

    float qv[HD];
    size_t qoff = ((size_t)(b*TT + s)*NN + n)*HH + head*HD;
    #pragma unroll
    for (int d = 0; d < HD; ++d) qv[d] = q[qoff + d];

    float sc[TT]; float mx = -1e30f;
    #pragma unroll
    for (int t = 0; t < TT; ++t) {
        size_t koff = ((size_t)(b*TT + t)*NN + n)*HH + head*HD;
        float a = 0.f;
        #pragma unroll
        for (int d = 0; d < HD; ++d) a += qv[d]*k[koff + d];
        a *= 0.35355339059327373f;
        sc[t] = a; mx = fmaxf(mx, a);
    }
    float sum = 0.f;
    #pragma unroll
    for (int t = 0; t < TT; ++t) { sc[t] = __expf(sc[t]-mx); sum += sc[t]; }
    float inv = 1.0f/sum;
    float ov[HD];
    #pragma unroll
    for (int d = 0; d < HD; ++d) ov[d] = 0.f;
    #pragma unroll
    for (int t = 0; t < TT; ++t) {
        size_t voff = ((size_t)(b*TT + t)*NN + n)*HH + head*HD;
        float a = sc[t]*inv;
        #pragma unroll
        for (int d = 0; d < HD; ++d) ov[d] += a*v[voff + d];
    }
    #pragma unroll
    for (int d = 0; d < HD; ++d) o[qoff + d] = ov[d];
}

// ---------------- 64x64 row-GEMM (4 rows/wave) ----------------
__global__ void k_rowgemm64(const float* __restrict__ in, const float* __restrict__ w,
                            const float* __restrict__ b, float* __restrict__ out)
{
    int gid = blockIdx.x*blockDim.x + threadIdx.x;
    int wv_ = gid >> 6; int j = gid & 63;
    int r0 = wv_*4;
    if (r0 >= RR) return;
    r0 = __builtin_amdgcn_readfirstlane(r0);
    const float* ir = in + (size_t)r0*HH;
    float bj = b[j];
    float a0=bj,a1=bj,a2=bj,a3=bj;
    #pragma unroll 8
    for (int c = 0; c < 64; ++c) {
        float wc = w[c*64 + j];
        a0 += ir[c]*wc; a1 += ir[HH+c]*wc; a2 += ir[2*HH+c]*wc; a3 += ir[3*HH+c]*wc;
    }
    out[(size_t)r0*HH + j]        = a0;
    out[(size_t)r0*HH + HH + j]   = a1;
    out[(size_t)r0*HH + 2*HH + j] = a2;
    out[(size_t)r0*HH + 3*HH + j] = a3;
}

// ---------------- fused conv(T->HOR) + MLP head ----------------
__global__ void k_convmlp(const float* __restrict__ h, const float* __restrict__ x,
                          const float* __restrict__ cw, const float* __restrict__ cb,
                          const float* __restrict__ w1, const float* __restrict__ b1,
                          const float* __restrict__ w2, const float* __restrict__ b2,
                          float* __restrict__ out)
{
    int gid = blockIdx.x*blockDim.x + threadIdx.x;
    if (gid >= BB*HORZ*NN) return;
    int n   = gid % NN;
    int hor = (gid/NN) % HORZ;
    int b   = gid/(NN*HORZ);

    float cwv[TT];
    #pragma unroll
    for (int t = 0; t < TT; ++t) cwv[t] = cw[hor*TT + t];
    float cbv = cb[hor];

    float z[72];
    #pragma unroll
    for (int c = 0; c < 72; ++c) z[c] = cbv;
    for (int t = 0; t < TT; ++t) {
        const float* hrow = h + ((size_t)(b*TT + t)*NN + n)*HH;
        const float* xrow = x + ((size_t)(b*TT + t)*NN + n)*CC;
        float wv = cwv[t];
        #pragma unroll
        for (int c = 0; c < 64; ++c) z[c]    += hrow[c]*wv;
        #pragma unroll
        for (int c = 0; c < 8; ++c)  z[64+c] += xrow[c]*wv;
    }

    float hid[64];
    #pragma unroll
    for (int k2 = 0; k2 < 64; ++k2) hid[k2] = b1[k2];
    #pragma unroll 2
    for (int c = 0; c < 72; ++c) {
        float v = z[c];
        #pragma unroll
        for (int k2 = 0; k2 < 64; ++k2) hid[k2] += v*w1[c*64 + k2];
    }
    #pragma unroll
    for (int k2 = 0; k2 < 64; ++k2) hid[k2] = fmaxf(hid[k2], 0.f);

    float o[8];
    #pragma unroll
    for (int c2 = 0; c2 < 8; ++c2) o[c2] = b2[c2];
    #pragma unroll 8
    for (int k2 = 0; k2 < 64; ++k2) {
        float v = hid[k2];
        #pragma unroll
        for (int c2 = 0; c2 < 8; ++c2) o[c2] += v*w2[k2*8 + c2];
    }
    size_t ooff = ((size_t)(b*HORZ + hor)*NN + n)*CC;
    #pragma unroll
    for (int c2 = 0; c2 < 8; ++c2) out[ooff + c2] = o[c2];
}

extern "C" void kernel_launch(void* const* d_in, const int* in_sizes, int n_in,
                              void* d_out, int out_size, void* d_ws, size_t ws_size,
                              hipStream_t stream) {
    const float* x    = (const float*)d_in[0];
    const int*   eidx = (const int*)d_in[1];
    const float* up_w = (const float*)d_in[2];
    const float* up_b = (const float*)d_in[3];
    const float* sp_w[2][10];
    for (int p = 0; p < 2; ++p)
        for (int i = 0; i < 10; ++i)
            sp_w[p][i] = (const float*)d_in[4 + p*10 + i];
    const float* wq = (const float*)d_in[24];
    const float* wk = (const float*)d_in[25];
    const float* wv = (const float*)d_in[26];
    const float* wo = (const float*)d_in[27];
    const float* bq = (const float*)d_in[28];
    const float* bk = (const float*)d_in[29];
    const float* bv = (const float*)d_in[30];
    const float* bo = (const float*)d_in[31];
    const float* conv_w = (const float*)d_in[32];
    const float* conv_b = (const float*)d_in[33];
    const float* mlp_w1 = (const float*)d_in[34];
    const float* mlp_b1 = (const float*)d_in[35];
    const float* mlp_w2 = (const float*)d_in[36];
    const float* mlp_b2 = (const float*)d_in[37];
    float* out = (float*)d_out;

    const size_t BUF = (size_t)RR*HH;      // 6,144,000 floats
    float* A    = (float*)d_ws;            // h
    float* Bb   = A   + BUF;               // h2
    float* AGG  = Bb  + BUF;               // agg / K
    float* Vb   = AGG + BUF;               // V
    float* Ob   = Vb  + BUF;               // attn out
    __bf16* PRE = (__bf16*)(Ob + BUF);     // per-node first-layer precompute (bf16)
    int*   cnt      = (int*)(PRE + BUF);   // 2048
    int*   ofs_work = cnt + 2048;          // 2048
    int*   ssrc     = ofs_work + 2048;     // EE
    int*   stgt     = ssrc + EE;           // EE
    __bf16* w2t0    = (__bf16*)(stgt + EE);// 2048 bf16
    __bf16* w2t1    = w2t0 + 2048;

    const int G4 = RR/16;                  // 6000 blocks of 256 (4 rows/wave)

    // ---- CSR build + weight prep ----
    hipMemsetAsync(cnt, 0, 2048*sizeof(int), stream);
    k_hist<<<(EE+255)/256, 256, 0, stream>>>(eidx, cnt);
    k_w2prep<<<8, 256, 0, stream>>>(sp_w[0][2], w2t0);
    k_w2prep<<<8, 256, 0, stream>>>(sp_w[1][2], w2t1);
    k_scan<<<1, 256, 0, stream>>>(cnt, ofs_work);
    k_scatter<<<(EE+255)/256, 256, 0, stream>>>(eidx, ofs_work, ssrc, stgt);

    // 1. up-projection
    k_up<<<G4, 256, 0, stream>>>(x, up_w, up_b, A);

    // 2. spatial 1
    hipMemsetAsync(AGG, 0, BUF*sizeof(float), stream);
    k_pre<<<G4, 256, 0, stream>>>(A, sp_w[0][0], PRE);
    k_msg<<<BT*(EE/64), 64, 0, stream>>>(PRE, ssrc, stgt,
        sp_w[0][1], w2t0, sp_w[0][3], sp_w[0][4], sp_w[0][5], AGG);
    k_upd<<<G4, 256, 0, stream>>>(A, AGG,
        sp_w[0][6], sp_w[0][7], sp_w[0][8], sp_w[0][9], Bb, 1);

    // 3. temporal: QKV (Q->A, K->AGG, V->Vb), attn -> Ob, proj -> A
    k_qkv<<<G4, 256, 0, stream>>>(Bb, wq, wk, wv, bq, bk, bv, A, AGG, Vb);
    k_attn<<<(BB*NN*NHEADS*TT + 255)/256, 256, 0, stream>>>(A, AGG, Vb, Ob);
    k_rowgemm64<<<G4, 256, 0, stream>>>(Ob, wo, bo, A);

    // 4. spatial 2
    hipMemsetAsync(AGG, 0, BUF*sizeof(float), stream);
    k_pre<<<G4, 256, 0, stream>>>(A, sp_w[1][0], PRE);
    k_msg<<<BT*(EE/64), 64, 0, stream>>>(PRE, ssrc, stgt,
        sp_w[1][1], w2t1, sp_w[1][3], sp_w[1][4], sp_w[1][5], AGG);
    k_upd<<<G4, 256, 0, stream>>>(A, AGG,
        sp_w[1][6], sp_w[1][7], sp_w[1][8], sp_w[1][9], Bb, 1);

    // 5. conv + MLP head -> out
    k_convmlp<<<(BB*HORZ*NN + 255)/256, 256, 0, stream>>>(Bb, x,
        conv_w, conv_b, mlp_w1, mlp_b1, mlp_w2, mlp_b2, out);
}

// Round 5
// 671.560 us; speedup vs baseline: 16.5179x; 1.0785x over previous
//
#include <hip/hip_runtime.h>
#include <math.h>

#define BB 4
#define TT 12
#define NN 2000
#define CC 8
#define HH 64
#define EE 32000
#define NHEADS 8
#define HD 8
#define HORZ 12
#define BT (BB*TT)        // 48
#define RR (BT*NN)        // 96000 rows of H=64

using bf16x8 = __attribute__((ext_vector_type(8))) __bf16;
using f16x8  = __attribute__((ext_vector_type(8))) _Float16;
using f16x4  = __attribute__((ext_vector_type(4))) _Float16;
using f32x4  = __attribute__((ext_vector_type(4))) float;

__device__ __forceinline__ float sigmoidf_(float x){ return 1.0f/(1.0f+__expf(-x)); }
__device__ __forceinline__ float siluf_(float x){ return x/(1.0f+__expf(-x)); }

// ================= CSR build (edges sorted by tgt) =================
__global__ void k_hist(const int* __restrict__ eidx, int* __restrict__ cnt) {
    int e = blockIdx.x*blockDim.x + threadIdx.x;
    if (e < EE) atomicAdd(&cnt[eidx[EE + e]], 1);
}

__global__ __launch_bounds__(256) void k_scan(const int* __restrict__ cnt,
                                              int* __restrict__ ofs_work) {
    __shared__ int part[256];
    int tid = threadIdx.x;
    int local[8]; int s = 0;
    #pragma unroll
    for (int k = 0; k < 8; ++k) {
        int idx = tid*8 + k;
        int v = (idx < NN) ? cnt[idx] : 0;
        local[k] = s; s += v;
    }
    part[tid] = s; __syncthreads();
    for (int off = 1; off < 256; off <<= 1) {
        int v = part[tid];
        int u = (tid >= off) ? part[tid-off] : 0;
        __syncthreads();
        part[tid] = v + u;
        __syncthreads();
    }
    int excl = part[tid] - s;
    #pragma unroll
    for (int k = 0; k < 8; ++k) {
        int idx = tid*8 + k;
        if (idx < NN) ofs_work[idx] = excl + local[k];
    }
}

__global__ void k_scatter(const int* __restrict__ eidx, int* __restrict__ ofs_work,
                          int* __restrict__ ssrc, int* __restrict__ stgt) {
    int e = blockIdx.x*blockDim.x + threadIdx.x;
    if (e >= EE) return;
    int t = eidx[EE + e];
    int pos = atomicAdd(&ofs_work[t], 1);
    ssrc[pos] = eidx[e];
    stgt[pos] = t;
}

// ========== W2 -> bf16, transposed to B-fragment-friendly [n][k] ==========
__global__ void k_w2prep(const float* __restrict__ w2, __bf16* __restrict__ w2t) {
    int i = blockIdx.x*blockDim.x + threadIdx.x;  // 2048 = 64 n * 32 k
    if (i >= 2048) return;
    int n = i >> 5, k = i & 31;
    w2t[i] = (__bf16)w2[k*64 + n];
}

// ========== per-node precompute of first msg-MLP layer (f16 out) ======
// preB[row][j]: j<32 -> (h_row @ W1_top)[j] (xi part), j>=32 -> (h_row @ W1_bot)[j-32]
__global__ void k_pre(const float* __restrict__ h, const float* __restrict__ w1,
                      _Float16* __restrict__ preB) {
    int gid = blockIdx.x*blockDim.x + threadIdx.x;
    int wv_ = gid >> 6; int j = gid & 63;
    int r0 = wv_*4;
    if (r0 >= RR) return;
    r0 = __builtin_amdgcn_readfirstlane(r0);
    const float* hr = h + (size_t)r0*HH;
    int base = (j < 32) ? j : (2048 + j - 32);
    float a0=0.f,a1=0.f,a2=0.f,a3=0.f;
    #pragma unroll 8
    for (int c = 0; c < 64; ++c) {
        float wc = w1[c*32 + base];
        a0 += hr[c]*wc; a1 += hr[HH+c]*wc; a2 += hr[2*HH+c]*wc; a3 += hr[3*HH+c]*wc;
    }
    preB[(size_t)r0*HH + j]        = (_Float16)a0;
    preB[(size_t)r0*HH + HH + j]   = (_Float16)a1;
    preB[(size_t)r0*HH + 2*HH + j] = (_Float16)a2;
    preB[(size_t)r0*HH + 3*HH + j] = (_Float16)a3;
}

// ========== message MLP + gate + indicator-MFMA segmented aggregation =====
__global__ __launch_bounds__(64) void k_msg(
    const _Float16* __restrict__ preB, const int* __restrict__ ssrc,
    const int* __restrict__ stgt,
    const float* __restrict__ b1,
    const __bf16* __restrict__ w2t, const float* __restrict__ b2,
    const float* __restrict__ gw, const float* __restrict__ gb,
    float* __restrict__ agg)
{
    const int EB = EE/64; // 500
    int eb = blockIdx.x % EB;
    int bt = blockIdx.x / EB;
    int t  = threadIdx.x;
    int l15 = t & 15, quad = t >> 4;

    union __align__(16) SM {
        __bf16   ab[64][40];     // layer-2 A-frag staging (stride 40 -> conflict-free b128)
        _Float16 bs[8][64][8];   // agg B-frag staging: [chunk*4+ni][lane][j]
    };
    __shared__ SM sm;
    __shared__ int segTgt[64];

    int e0 = eb*64;
    int my_src = ssrc[e0 + t];
    int my_tgt = stgt[e0 + t];

    // ---- segment ids within window (edges sorted by tgt) ----
    int prevt = __shfl(my_tgt, (t + 63) & 63);
    bool bnd = (t == 0) || (prevt != my_tgt);
    unsigned long long bm = __ballot(bnd);
    int seg = __builtin_amdgcn_mbcnt_hi((unsigned)(bm >> 32),
              __builtin_amdgcn_mbcnt_lo((unsigned)bm, 0u));
    int nseg = __popcll(bm);
    if (bnd) segTgt[seg] = my_tgt;

    // ---- direct register gather + factored layer 1 (lane t = edge e0+t) ----
    const _Float16* basep = preB + (size_t)bt*NN*HH;
    const _Float16* rT = basep + (size_t)my_tgt*HH;        // xi part: cols 0..31
    const _Float16* rS = basep + (size_t)my_src*HH + 32;   // xj part: cols 32..63
    f16x8 xi[4], xj[4];
    #pragma unroll
    for (int g4 = 0; g4 < 4; ++g4) {
        xi[g4] = *(const f16x8*)&rT[8*g4];
        xj[g4] = *(const f16x8*)&rS[8*g4];
    }
    #pragma unroll
    for (int g4 = 0; g4 < 4; ++g4) {
        bf16x8 v;
        #pragma unroll
        for (int u = 0; u < 8; ++u) {
            float m = (float)xi[g4][u] + (float)xj[g4][u] + b1[8*g4 + u];
            v[u] = (__bf16)siluf_(m);
        }
        ((bf16x8*)&sm.ab[t][0])[g4] = v;
    }

    // B fragments of W2^T (bf16, [n][k]) + bias/gate vectors
    bf16x8 bfr[4];
    float b2v[4], gwv[4];
    #pragma unroll
    for (int ni = 0; ni < 4; ++ni) {
        bfr[ni] = *(const bf16x8*)&w2t[(16*ni + l15)*32 + quad*8];
        b2v[ni] = b2[16*ni + l15];
        gwv[ni] = gw[16*ni + l15];
    }
    float gb0 = gb[0];

    __syncthreads();  // ab + segTgt visible

    // ---- layer 2: 64x64 = 4x4 tiles, K=32 one MFMA each ----
    f32x4 acc[4][4];
    #pragma unroll
    for (int mi = 0; mi < 4; ++mi) {
        bf16x8 af = *(const bf16x8*)&sm.ab[16*mi + l15][quad*8];
        #pragma unroll
        for (int ni = 0; ni < 4; ++ni) {
            f32x4 z = {0.f, 0.f, 0.f, 0.f};
            acc[mi][ni] = __builtin_amdgcn_mfma_f32_16x16x32_bf16(af, bfr[ni], z, 0, 0, 0);
        }
    }
    __syncthreads();  // ab frag reads done; union region free for bs

    // ---- epilogue: silu + gate, stash P = g*m2 in B-frag layout (f16) ----
    #pragma unroll
    for (int mi = 0; mi < 4; ++mi) {
        float sv[4][4]; // [ni][rg]
        #pragma unroll
        for (int ni = 0; ni < 4; ++ni)
            #pragma unroll
            for (int rg = 0; rg < 4; ++rg)
                sv[ni][rg] = siluf_(acc[mi][ni][rg] + b2v[ni]);
        float gg[4];
        #pragma unroll
        for (int rg = 0; rg < 4; ++rg) {
            float p = sv[0][rg]*gwv[0] + sv[1][rg]*gwv[1]
                    + sv[2][rg]*gwv[2] + sv[3][rg]*gwv[3];
            p += __shfl_xor(p, 1); p += __shfl_xor(p, 2);
            p += __shfl_xor(p, 4); p += __shfl_xor(p, 8);
            gg[rg] = sigmoidf_(p + gb0);
        }
        // write: value (er=16mi+4quad+rg, col=16ni+l15) -> bs[chunk*4+ni][16*qb+l15][j]
        int c  = mi >> 1;
        int qb = 2*(mi & 1) + (quad >> 1);
        int j0 = 4*(quad & 1);
        #pragma unroll
        for (int ni = 0; ni < 4; ++ni) {
            f16x4 pk;
            #pragma unroll
            for (int rg = 0; rg < 4; ++rg) pk[rg] = (_Float16)(sv[ni][rg]*gg[rg]);
            *(f16x4*)&sm.bs[c*4 + ni][16*qb + l15][j0] = pk;
        }
    }
    __syncthreads();  // bs visible

    // ---- indicator-MFMA segmented aggregation ----
    f16x8 bfrag[2][4];
    #pragma unroll
    for (int c = 0; c < 2; ++c)
        #pragma unroll
        for (int ni = 0; ni < 4; ++ni)
            bfrag[c][ni] = *(const f16x8*)&sm.bs[c*4 + ni][t][0];

    float* ap = agg + (size_t)bt*NN*HH;
    for (int g0 = 0; g0 < nseg; g0 += 16) {
        f16x8 ind[2];
        #pragma unroll
        for (int c = 0; c < 2; ++c) {
            #pragma unroll
            for (int j = 0; j < 8; ++j) {
                int sj = __shfl(seg, 32*c + 8*quad + j);
                ind[c][j] = (sj == g0 + l15) ? (_Float16)1.0f : (_Float16)0.0f;
            }
        }
        f32x4 av[4];
        #pragma unroll
        for (int ni = 0; ni < 4; ++ni) {
            f32x4 z = {0.f, 0.f, 0.f, 0.f};
            av[ni] = __builtin_amdgcn_mfma_f32_16x16x32_f16(ind[0], bfrag[0][ni], z, 0, 0, 0);
            av[ni] = __builtin_amdgcn_mfma_f32_16x16x32_f16(ind[1], bfrag[1][ni], av[ni], 0, 0, 0);
        }
        #pragma unroll
        for (int rg = 0; rg < 4; ++rg) {
            int s = g0 + 4*quad + rg;   // C layout: row = quad*4 + reg
            if (s < nseg) {
                int tn = segTgt[s];
                #pragma unroll
                for (int ni = 0; ni < 4; ++ni)
                    atomicAdd(&ap[(size_t)tn*HH + 16*ni + l15], av[ni][rg]);
            }
        }
    }
}

// ---------------- up-projection (4 rows/wave) ----------------
__global__ void k_up(const float* __restrict__ x, const float* __restrict__ w,
                     const float* __restrict__ b, float* __restrict__ h) {
    int gid = blockIdx.x*blockDim.x + threadIdx.x;
    int wv_ = gid >> 6; int j = gid & 63;
    int r0 = wv_*4;
    if (r0 >= RR) return;
    r0 = __builtin_amdgcn_readfirstlane(r0);
    const float* xr = x + (size_t)r0*CC;
    float bj = b[j];
    float a0=bj,a1=bj,a2=bj,a3=bj;
    #pragma unroll
    for (int c = 0; c < CC; ++c) {
        float wc = w[c*HH + j];
        a0 += xr[c]*wc; a1 += xr[CC+c]*wc; a2 += xr[2*CC+c]*wc; a3 += xr[3*CC+c]*wc;
    }
    h[(size_t)r0*HH + j]        = fmaxf(a0, 0.f);
    h[(size_t)r0*HH + HH + j]   = fmaxf(a1, 0.f);
    h[(size_t)r0*HH + 2*HH + j] = fmaxf(a2, 0.f);
    h[(size_t)r0*HH + 3*HH + j] = fmaxf(a3, 0.f);
}

// ---------------- spatial update (4 rows/wave) ----------------
__global__ void k_upd(const float* __restrict__ h, const float* __restrict__ agg,
                      const float* __restrict__ w1, const float* __restrict__ b1,
                      const float* __restrict__ w2, const float* __restrict__ b2,
                      float* __restrict__ out, int do_relu)
{
    int gid = blockIdx.x*blockDim.x + threadIdx.x;
    int wv_ = gid >> 6; int j = gid & 63;
    int r0 = wv_*4;
    if (r0 >= RR) return;
    r0 = __builtin_amdgcn_readfirstlane(r0);
    const float* ar = agg + (size_t)r0*HH;
    const float* hr = h   + (size_t)r0*HH;
    float bj = b1[j];
    float a0=bj,a1=bj,a2=bj,a3=bj;
    #pragma unroll 8
    for (int c = 0; c < 64; ++c) {
        float wv = w1[c*64 + j];
        a0 += ar[c]*wv; a1 += ar[HH+c]*wv; a2 += ar[2*HH+c]*wv; a3 += ar[3*HH+c]*wv;
    }
    #pragma unroll 8
    for (int c = 0; c < 64; ++c) {
        float wv = w1[(64+c)*64 + j];
        a0 += hr[c]*wv; a1 += hr[HH+c]*wv; a2 += hr[2*HH+c]*wv; a3 += hr[3*HH+c]*wv;
    }
    float u0=siluf_(a0), u1=siluf_(a1), u2=siluf_(a2), u3=siluf_(a3);
    float b2j = b2[j];
    float c0=b2j,c1=b2j,c2=b2j,c3=b2j;
    #pragma unroll 8
    for (int k2 = 0; k2 < 64; ++k2) {
        float wv = w2[k2*64 + j];
        c0 += __shfl(u0,k2)*wv; c1 += __shfl(u1,k2)*wv;
        c2 += __shfl(u2,k2)*wv; c3 += __shfl(u3,k2)*wv;
    }
    float o0 = c0 + hr[j],        o1 = c1 + hr[HH+j];
    float o2 = c2 + hr[2*HH+j],   o3 = c3 + hr[3*HH+j];
    if (do_relu) { o0=fmaxf(o0,0.f); o1=fmaxf(o1,0.f); o2=fmaxf(o2,0.f); o3=fmaxf(o3,0.f); }
    out[(size_t)r0*HH + j]        = o0;
    out[(size_t)r0*HH + HH + j]   = o1;
    out[(size_t)r0*HH + 2*HH + j] = o2;
    out[(size_t)r0*HH + 3*HH + j] = o3;
}

// ---------------- fused QKV projection (4 rows/wave) ----------------
__global__ void k_qkv(const float* __restrict__ h,
                      const float* __restrict__ wq, const float* __restrict__ wk,
                      const float* __restrict__ wv,
                      const float* __restrict__ bq, const float* __restrict__ bk,
                      const float* __restrict__ bv,
                      float* __restrict__ q, float* __restrict__ k, float* __restrict__ v)
{
    int gid = blockIdx.x*blockDim.x + threadIdx.x;
    int wv_ = gid >> 6; int j = gid & 63;
    int r0 = wv_*4;
    if (r0 >= RR) return;
    r0 = __builtin_amdgcn_readfirstlane(r0);
    const float* hr = h + (size_t)r0*HH;
    float q0=bq[j],q1=q0,q2=q0,q3=q0;
    float k0=bk[j],k1=k0,k2v=k0,k3=k0;
    float v0=bv[j],v1=v0,v2=v0,v3=v0;
    #pragma unroll 4
    for (int c = 0; c < 64; ++c) {
        float wqc = wq[c*64 + j], wkc = wk[c*64 + j], wvc = wv[c*64 + j];
        float h0 = hr[c], h1 = hr[HH+c], h2 = hr[2*HH+c], h3 = hr[3*HH+c];
        q0 += h0*wqc; q1 += h1*wqc; q2 += h2*wqc; q3 += h3*wqc;
        k0 += h0*wkc; k1 += h1*wkc; k2v += h2*wkc; k3 += h3*wkc;
        v0 += h0*wvc; v1 += h1*wvc; v2 += h2*wvc; v3 += h3*wvc;
    }
    size_t o = (size_t)r0*HH + j;
    q[o]=q0; q[o+HH]=q1; q[o+2*HH]=q2; q[o+3*HH]=q3;
    k[o]=k0; k[o+HH]=k1; k[o+2*HH]=k2v; k[o+3*HH]=k3;
    v[o]=v0; v[o+HH]=v1; v[o+2*HH]=v2; v[o+3*HH]=v3;
}

// ---------------- temporal attention (T=12, per (b,n,head,s) thread) ------
__global__ void k_attn(const float* __restrict__ q, const float* __restrict__ k,
                       const float* __restrict__ v, float* __restrict__ o)
{
    int gid = blockIdx.x*blockDim.x + threadIdx.x;
    if (gid >= BB*NN*NHEADS*TT) return;
    int s    = gid % TT;
    int head = (gid/TT) % NHEADS;
    int n    = (gid/(TT*NHEADS)) % NN;
    int b    = gid/(TT*NHEADS*NN);

    float qv[HD];
    size_t qoff = ((size_t)(b*TT + s)*NN + n)*HH + head*HD;
    #pragma unroll
    for (int d = 0; d < HD; ++d) qv[d] = q[qoff + d];

    float sc[TT]; float mx = -1e30f;
    #pragma unroll
    for (int t = 0; t < TT; ++t) {
        size_t koff = ((size_t)(b*TT + t)*NN + n)*HH + head*HD;
        float a = 0.f;
        #pragma unroll
        for (int d = 0; d < HD; ++d) a += qv[d]*k[koff + d];
        a *= 0.35355339059327373f;
        sc[t] = a; mx = fmaxf(mx, a);
    }
    float sum = 0.f;
    #pragma unroll
    for (int t = 0; t < TT; ++t) { sc[t] = __expf(sc[t]-mx); sum += sc[t]; }
    float inv = 1.0f/sum;
    float ov[HD];
    #pragma unroll
    for (int d = 0; d < HD; ++d) ov[d] = 0.f;
    #pragma unroll
    for (int t = 0; t < TT; ++t) {
        size_t voff = ((size_t)(b*TT + t)*NN + n)*HH + head*HD;
        float a = sc[t]*inv;
        #pragma unroll
        for (int d = 0; d < HD; ++d) ov[d] += a*v[voff + d];
    }
    #pragma unroll
    for (int d = 0; d < HD; ++d) o[qoff + d] = ov[d];
}

// ---------------- 64x64 row-GEMM (4 rows/wave) ----------------
__global__ void k_rowgemm64(const float* __restrict__ in, const float* __restrict__ w,
                            const float* __restrict__ b, float* __restrict__ out)
{
    int gid = blockIdx.x*blockDim.x + threadIdx.x;
    int wv_ = gid >> 6; int j = gid & 63;
    int r0 = wv_*4;
    if (r0 >= RR) return;
    r0 = __builtin_amdgcn_readfirstlane(r0);
    const float* ir = in + (size_t)r0*HH;
    float bj = b[j];
    float a0=bj,a1=bj,a2=bj,a3=bj;
    #pragma unroll 8
    for (int c = 0; c < 64; ++c) {
        float wc = w[c*64 + j];
        a0 += ir[c]*wc; a1 += ir[HH+c]*wc; a2 += ir[2*HH+c]*wc; a3 += ir[3*HH+c]*wc;
    }
    out[(size_t)r0*HH + j]        = a0;
    out[(size_t)r0*HH + HH + j]   = a1;
    out[(size_t)r0*HH + 2*HH + j] = a2;
    out[(size_t)r0*HH + 3*HH + j] = a3;
}

// ---------------- conv head stage 1: z[b,hor,n,0:72] = conv over t -------
// wave per (b,n); lane j = feature. All accumulators in registers.
__global__ __launch_bounds__(256) void k_zbuild(
    const float* __restrict__ h, const float* __restrict__ x,
    const float* __restrict__ cw, const float* __restrict__ cb,
    float* __restrict__ z)
{
    int gid = blockIdx.x*blockDim.x + threadIdx.x;
    int p = gid >> 6;          // (b,n) pair, 8000 total
    int j = gid & 63;
    if (p >= BB*NN) return;
    p = __builtin_amdgcn_readfirstlane(p);
    int b = p / NN, n = p % NN;

    float hv[TT];
    #pragma unroll
    for (int t = 0; t < TT; ++t)
        hv[t] = h[((size_t)(b*TT + t)*NN + n)*HH + j];
    float xv[TT];
    if (j < CC) {
        #pragma unroll
        for (int t = 0; t < TT; ++t)
            xv[t] = x[((size_t)(b*TT + t)*NN + n)*CC + j];
    }

    #pragma unroll
    for (int hor = 0; hor < HORZ; ++hor) {
        float cbv = cb[hor];
        float zh = cbv, zx = cbv;
        #pragma unroll
        for (int t = 0; t < TT; ++t) {
            float w = cw[hor*TT + t];
            zh += w*hv[t];
            if (j < CC) zx += w*xv[t];
        }
        size_t row = (size_t)(b*HORZ + hor)*NN + n;
        z[row*72 + j] = zh;
        if (j < CC) z[row*72 + 64 + j] = zx;
    }
}

// ---------------- conv head stage 2: out = relu(z@w1+b1)@w2+b2 ----------
// 4 rows/wave; layer-2 via per-wave LDS broadcast (no spills, no shuffles).
__global__ __launch_bounds__(256) void k_headmlp(
    const float* __restrict__ z,
    const float* __restrict__ w1, const float* __restrict__ b1,
    const float* __restrict__ w2, const float* __restrict__ b2,
    float* __restrict__ out)
{
    __shared__ float U[4][4][65];
    int gid = blockIdx.x*blockDim.x + threadIdx.x;
    int wv_ = gid >> 6; int j = gid & 63;
    int wl = threadIdx.x >> 6;
    int r0 = wv_*4;               // BB*HORZ*NN = 96000, divisible by 4 -> no tail
    r0 = __builtin_amdgcn_readfirstlane(r0);
    const float* zr = z + (size_t)r0*72;
    float bj = b1[j];
    float a0=bj,a1=bj,a2=bj,a3=bj;
    #pragma unroll 8
    for (int c = 0; c < 72; ++c) {
        float wc = w1[c*64 + j];
        a0 += zr[c]*wc; a1 += zr[72+c]*wc; a2 += zr[144+c]*wc; a3 += zr[216+c]*wc;
    }
    U[wl][0][j] = fmaxf(a0, 0.f);
    U[wl][1][j] = fmaxf(a1, 0.f);
    U[wl][2][j] = fmaxf(a2, 0.f);
    U[wl][3][j] = fmaxf(a3, 0.f);
    __syncthreads();

    if (j < 32) {
        int r = j >> 3, c = j & 7;
        float o = b2[c];
        #pragma unroll 8
        for (int k = 0; k < 64; ++k)
            o += U[wl][r][k] * w2[k*8 + c];
        out[(size_t)(r0 + r)*CC + c] = o;
    }
}

extern "C" void kernel_launch(void* const* d_in, const int* in_sizes, int n_in,
                              void* d_out, int out_size, void* d_ws, size_t ws_size,
                              hipStream_t stream) {
    const float* x    = (const float*)d_in[0];
    const int*   eidx = (const int*)d_in[1];
    const float* up_w = (const float*)d_in[2];
    const float* up_b = (const float*)d_in[3];
    const float* sp_w[2][10];
    for (int p = 0; p < 2; ++p)
        for (int i = 0; i < 10; ++i)
            sp_w[p][i] = (const float*)d_in[4 + p*10 + i];
    const float* wq = (const float*)d_in[24];
    const float* wk = (const float*)d_in[25];
    const float* wv = (const float*)d_in[26];
    const float* wo = (const float*)d_in[27];
    const float* bq = (const float*)d_in[28];
    const float* bk = (const float*)d_in[29];
    const float* bv = (const float*)d_in[30];
    const float* bo = (const float*)d_in[31];
    const float* conv_w = (const float*)d_in[32];
    const float* conv_b = (const float*)d_in[33];
    const float* mlp_w1 = (const float*)d_in[34];
    const float* mlp_b1 = (const float*)d_in[35];
    const float* mlp_w2 = (const float*)d_in[36];
    const float* mlp_b2 = (const float*)d_in[37];
    float* out = (float*)d_out;

    const size_t BUF = (size_t)RR*HH;      // 6,144,000 floats
    float* A    = (float*)d_ws;            // h
    float* Bb   = A   + BUF;               // h2
    float* AGG  = Bb  + BUF;               // agg / K
    float* Vb   = AGG + BUF;               // V
    float* Ob   = Vb  + BUF;               // attn out
    _Float16* PRE = (_Float16*)(Ob + BUF); // per-node first-layer precompute (f16)
    int*   cnt      = (int*)(PRE + BUF);   // 2048
    int*   ofs_work = cnt + 2048;          // 2048
    int*   ssrc     = ofs_work + 2048;     // EE
    int*   stgt     = ssrc + EE;           // EE
    __bf16* w2t0    = (__bf16*)(stgt + EE);// 2048 bf16
    __bf16* w2t1    = w2t0 + 2048;
    float* Z = AGG;   // reuse AGG+Vb region (49 MB) for z[96000*72] = 27.6 MB

    const int G4 = RR/16;                  // 6000 blocks of 256 (4 rows/wave)

    // ---- CSR build + weight prep ----
    hipMemsetAsync(cnt, 0, 2048*sizeof(int), stream);
    k_hist<<<(EE+255)/256, 256, 0, stream>>>(eidx, cnt);
    k_w2prep<<<8, 256, 0, stream>>>(sp_w[0][2], w2t0);
    k_w2prep<<<8, 256, 0, stream>>>(sp_w[1][2], w2t1);
    k_scan<<<1, 256, 0, stream>>>(cnt, ofs_work);
    k_scatter<<<(EE+255)/256, 256, 0, stream>>>(eidx, ofs_work, ssrc, stgt);

    // 1. up-projection
    k_up<<<G4, 256, 0, stream>>>(x, up_w, up_b, A);

    // 2. spatial 1
    hipMemsetAsync(AGG, 0, BUF*sizeof(float), stream);
    k_pre<<<G4, 256, 0, stream>>>(A, sp_w[0][0], PRE);
    k_msg<<<BT*(EE/64), 64, 0, stream>>>(PRE, ssrc, stgt,
        sp_w[0][1], w2t0, sp_w[0][3], sp_w[0][4], sp_w[0][5], AGG);
    k_upd<<<G4, 256, 0, stream>>>(A, AGG,
        sp_w[0][6], sp_w[0][7], sp_w[0][8], sp_w[0][9], Bb, 1);

    // 3. temporal: QKV (Q->A, K->AGG, V->Vb), attn -> Ob, proj -> A
    k_qkv<<<G4, 256, 0, stream>>>(Bb, wq, wk, wv, bq, bk, bv, A, AGG, Vb);
    k_attn<<<(BB*NN*NHEADS*TT + 255)/256, 256, 0, stream>>>(A, AGG, Vb, Ob);
    k_rowgemm64<<<G4, 256, 0, stream>>>(Ob, wo, bo, A);

    // 4. spatial 2
    hipMemsetAsync(AGG, 0, BUF*sizeof(float), stream);
    k_pre<<<G4, 256, 0, stream>>>(A, sp_w[1][0], PRE);
    k_msg<<<BT*(EE/64), 64, 0, stream>>>(PRE, ssrc, stgt,
        sp_w[1][1], w2t1, sp_w[1][3], sp_w[1][4], sp_w[1][5], AGG);
    k_upd<<<G4, 256, 0, stream>>>(A, AGG,
        sp_w[1][6], sp_w[1][7], sp_w[1][8], sp_w[1][9], Bb, 1);

    // 5. conv + MLP head: zbuild (Z overlays AGG/Vb, both dead now) -> out
    k_zbuild<<<(BB*NN*64 + 255)/256, 256, 0, stream>>>(Bb, x, conv_w, conv_b, Z);
    k_headmlp<<<(BB*HORZ*NN)/16, 256, 0, stream>>>(Z,
        mlp_w1, mlp_b1, mlp_w2, mlp_b2, out);
}